// Round 1
// baseline (877.259 us; speedup 1.0000x reference)
//
#include <hip/hip_runtime.h>
#include <math.h>

#define BB 2
#define HHH 56
#define WWW 56
#define CC 192
#define LL 3136
#define DI 384
#define KK 4
#define NN 16
#define RR 12
#define CP 44
#define HIDN 768
#define BL (BB*LL)

__device__ __forceinline__ float siluf_(float x){ return x/(1.f+__expf(-x)); }
__device__ __forceinline__ float softplusf_(float x){ return fmaxf(x,0.f) + log1pf(__expf(-fabsf(x))); }
__device__ __forceinline__ float geluf_(float x){ return 0.5f*x*(1.f+erff(x*0.70710678118654752f)); }

// ---------------- depthwise 3x3 + residual (NHWC, C=192) ----------------
__global__ void k_dwconv_res(const float* __restrict__ in, const float* __restrict__ wgt,
                             const float* __restrict__ bias, float* __restrict__ out) {
  int idx = blockIdx.x*256 + threadIdx.x;
  const int total = BB*HHH*WWW*CC;
  if (idx >= total) return;
  int c = idx % CC;
  int w = (idx / CC) % WWW;
  int h = (idx / (CC*WWW)) % HHH;
  int b = idx / (CC*WWW*HHH);
  float acc = bias[c];
  #pragma unroll
  for (int kh=0; kh<3; kh++){
    int hh = h + kh - 1; if (hh < 0 || hh >= HHH) continue;
    #pragma unroll
    for (int kw=0; kw<3; kw++){
      int ww = w + kw - 1; if (ww < 0 || ww >= WWW) continue;
      acc += in[((b*HHH+hh)*WWW+ww)*CC + c] * wgt[c*9 + kh*3 + kw];
    }
  }
  out[idx] = in[idx] + acc;
}

// ---------------- LayerNorm over D=192, one wave per row ----------------
__global__ void k_ln192(const float* __restrict__ in, const float* __restrict__ g,
                        const float* __restrict__ bta, float* __restrict__ out, float eps) {
  int row = blockIdx.x*4 + (threadIdx.x>>6);
  int lane = threadIdx.x & 63;
  const float* p = in + (size_t)row*CC;
  float v0=p[lane], v1=p[lane+64], v2=p[lane+128];
  float s = v0+v1+v2, s2 = v0*v0+v1*v1+v2*v2;
  #pragma unroll
  for (int off=1; off<64; off<<=1){ s += __shfl_xor(s,off); s2 += __shfl_xor(s2,off); }
  float m = s*(1.f/192.f);
  float var = s2*(1.f/192.f) - m*m;
  float rstd = rsqrtf(var + eps);
  float* q = out + (size_t)row*CC;
  q[lane]     = (v0-m)*rstd*g[lane]     + bta[lane];
  q[lane+64]  = (v1-m)*rstd*g[lane+64]  + bta[lane+64];
  q[lane+128] = (v2-m)*rstd*g[lane+128] + bta[lane+128];
}

// ---------------- fp32 GEMM: out(MxN) = A(MxK) * W(NxK)^T, tile 64x64 ----------------
enum { EPI_NONE=0, EPI_RES=1, EPI_BIAS_GELU=2, EPI_BIAS_RES=3 };

template<int EPI>
__global__ __launch_bounds__(256) void k_gemm(const float* __restrict__ A, const float* __restrict__ Wt,
            const float* __restrict__ bias, const float* __restrict__ res,
            float* __restrict__ out, int M, int Nn, int Kk) {
  __shared__ float As[16][68];
  __shared__ float Bs[16][68];
  int tid = threadIdx.x;
  int m0 = blockIdx.y*64, n0 = blockIdx.x*64;
  int tm = tid & 15, tn = tid >> 4;
  int ldr = tid >> 2, ldc = (tid & 3)*4;
  float acc[4][4];
  #pragma unroll
  for (int i=0;i<4;i++)
    #pragma unroll
    for (int j=0;j<4;j++) acc[i][j]=0.f;
  const float* Ap = A  + (size_t)(m0+ldr)*Kk + ldc;
  const float* Wp = Wt + (size_t)(n0+ldr)*Kk + ldc;
  for (int k0=0; k0<Kk; k0+=16) {
    float4 a  = *(const float4*)(Ap + k0);
    float4 bw = *(const float4*)(Wp + k0);
    __syncthreads();
    As[ldc+0][ldr]=a.x;  As[ldc+1][ldr]=a.y;  As[ldc+2][ldr]=a.z;  As[ldc+3][ldr]=a.w;
    Bs[ldc+0][ldr]=bw.x; Bs[ldc+1][ldr]=bw.y; Bs[ldc+2][ldr]=bw.z; Bs[ldc+3][ldr]=bw.w;
    __syncthreads();
    #pragma unroll
    for (int kk=0; kk<16; kk++){
      float4 av = *(const float4*)&As[kk][tm*4];
      float4 bv = *(const float4*)&Bs[kk][tn*4];
      float am[4] = {av.x, av.y, av.z, av.w};
      float bn[4] = {bv.x, bv.y, bv.z, bv.w};
      #pragma unroll
      for (int i=0;i<4;i++)
        #pragma unroll
        for (int j=0;j<4;j++) acc[i][j] = fmaf(am[i], bn[j], acc[i][j]);
    }
  }
  #pragma unroll
  for (int i=0;i<4;i++){
    int m = m0 + tm*4 + i;
    int n = n0 + tn*4;
    float o[4] = {acc[i][0], acc[i][1], acc[i][2], acc[i][3]};
    if (EPI==EPI_BIAS_GELU || EPI==EPI_BIAS_RES){
      const float4 bs = *(const float4*)&bias[n];
      o[0]+=bs.x; o[1]+=bs.y; o[2]+=bs.z; o[3]+=bs.w;
    }
    if (EPI==EPI_BIAS_GELU){
      #pragma unroll
      for (int j=0;j<4;j++) o[j] = geluf_(o[j]);
    }
    if (EPI==EPI_RES || EPI==EPI_BIAS_RES){
      const float4 rv = *(const float4*)&res[(size_t)m*Nn + n];
      o[0]+=rv.x; o[1]+=rv.y; o[2]+=rv.z; o[3]+=rv.w;
    }
    float4 ov = make_float4(o[0],o[1],o[2],o[3]);
    *(float4*)&out[(size_t)m*Nn + n] = ov;
  }
}

// ---------------- depthwise conv 3x3 + bias + SiLU on xx half of xz ----------------
__global__ void k_conv_xx(const float* __restrict__ xz, const float* __restrict__ cw,
                          const float* __restrict__ cb, float* __restrict__ xc) {
  int idx = blockIdx.x*256 + threadIdx.x;
  if (idx >= BB*LL*DI) return;
  int d = idx % DI;
  int l = (idx / DI) % LL;
  int b = idx / (DI*LL);
  int h = l / WWW, w = l % WWW;
  float acc = cb[d];
  #pragma unroll
  for (int kh=0; kh<3; kh++){
    int hh = h + kh - 1; if (hh < 0 || hh >= HHH) continue;
    #pragma unroll
    for (int kw=0; kw<3; kw++){
      int ww2 = w + kw - 1; if (ww2 < 0 || ww2 >= WWW) continue;
      acc += xz[((size_t)(b*LL + hh*WWW + ww2))*(2*DI) + d] * cw[d*9 + kh*3 + kw];
    }
  }
  xc[idx] = siluf_(acc);
}

// ---------------- (B,L,Di) -> (B,Di,L) transpose ----------------
__global__ void k_trans_dl(const float* __restrict__ in, float* __restrict__ out) {
  __shared__ float t[32][33];
  int b = blockIdx.x, l0 = blockIdx.y*32, d0 = blockIdx.z*32;
  int tx = threadIdx.x, ty = threadIdx.y;
  #pragma unroll
  for (int r=0;r<4;r++){ int lr = ty + r*8;
    t[lr][tx] = in[((size_t)(b*LL + l0+lr))*DI + d0 + tx]; }
  __syncthreads();
  #pragma unroll
  for (int r=0;r<4;r++){ int dr = ty + r*8;
    out[((size_t)(b*DI + d0+dr))*LL + l0 + tx] = t[tx][dr]; }
}

// ---------------- (B,L,Di) -> (B,Di,L1) with l1 = w*H + h ----------------
__global__ void k_trans_T(const float* __restrict__ in, float* __restrict__ out) {
  __shared__ float t[32][33];
  int bw = blockIdx.x;
  int b = bw / WWW, w = bw % WWW;
  int h0 = blockIdx.y*32, d0 = blockIdx.z*32;
  int tx = threadIdx.x, ty = threadIdx.y;
  #pragma unroll
  for (int r=0;r<4;r++){ int hr = ty + r*8; int h = h0 + hr;
    if (h < HHH) t[hr][tx] = in[((size_t)(b*LL + h*WWW + w))*DI + d0 + tx]; }
  __syncthreads();
  #pragma unroll
  for (int r=0;r<4;r++){ int dr = ty + r*8; int h = h0 + tx;
    if (h < HHH) out[((size_t)(b*DI + d0+dr))*LL + w*HHH + h] = t[tx][dr]; }
}

// ---------------- x_dbl[b,k,c,l] = sum_d u_k(b,d,l) * xpw[k,c,d] ----------------
__global__ __launch_bounds__(256) void k_xdbl(const float* __restrict__ xc_dl, const float* __restrict__ xcT,
        const float* __restrict__ xpw, float* __restrict__ xdbl) {
  __shared__ float wsm[CP][32];
  int bk = blockIdx.x;
  int b = bk / KK, k = bk % KK;
  int l = blockIdx.y*64 + threadIdx.x;
  int cslot = threadIdx.y;
  const float* usrc = (k & 1) ? xcT : xc_dl;
  int lidx = (k < 2) ? l : (LL-1-l);
  float acc[11];
  #pragma unroll
  for (int j=0;j<11;j++) acc[j]=0.f;
  int tid = threadIdx.y*64 + threadIdx.x;
  for (int d0=0; d0<DI; d0+=32) {
    __syncthreads();
    for (int idx=tid; idx<CP*32; idx+=256) {
      int c = idx >> 5, dd = idx & 31;
      wsm[c][dd] = xpw[(k*CP + c)*DI + d0 + dd];
    }
    __syncthreads();
    #pragma unroll
    for (int dd=0; dd<32; dd++) {
      float u = usrc[((size_t)(b*DI + d0+dd))*LL + lidx];
      #pragma unroll
      for (int j=0;j<11;j++) acc[j] = fmaf(u, wsm[cslot*11+j][dd], acc[j]);
    }
  }
  size_t base = ((size_t)bk*CP)*LL + l;
  #pragma unroll
  for (int j=0;j<11;j++) xdbl[base + (size_t)(cslot*11+j)*LL] = acc[j];
}

// ---------------- selective scan: one wave per (b,k, 4-d block) ----------------
__global__ __launch_bounds__(64) void k_scan(const float* __restrict__ xc_dl, const float* __restrict__ xcT,
        const float* __restrict__ xdbl, const float* __restrict__ dtw, const float* __restrict__ dtb,
        const float* __restrict__ alogs, const float* __restrict__ Dsv, float* __restrict__ ys) {
  __shared__ float dt_s[4][68], u_s[4][68], B_s[16][68], C_s[16][68], y_s[4][68];
  int bid = blockIdx.x;
  int dblk = bid % 96;
  int k = (bid / 96) % KK;
  int b = bid / (96*KK);
  int lane = threadIdx.x;
  int n = lane & 15, dl = lane >> 4;
  int d = dblk*4 + dl;
  float Acoef = -__expf(alogs[(k*DI + d)*NN + n]);
  float Dd = Dsv[k*DI + d];
  float dtw_r[4][12]; float dtb_r[4];
  #pragma unroll
  for (int dd=0; dd<4; dd++){
    dtb_r[dd] = dtb[k*DI + dblk*4 + dd];
    #pragma unroll
    for (int r=0;r<12;r++) dtw_r[dd][r] = dtw[(k*DI + dblk*4+dd)*RR + r];
  }
  const float* usrc = (k & 1) ? xcT : xc_dl;
  const float* xd = xdbl + ((size_t)(b*KK + k)*CP)*LL;
  bool rev = (k >= 2);
  float h = 0.f;
  size_t ubase  = ((size_t)(b*DI + dblk*4))*LL;
  size_t ysbase = ((size_t)((b*KK + k)*DI + dblk*4))*LL;
  for (int lc0=0; lc0<LL; lc0+=64) {
    int li = lc0 + lane;
    int lsrc = rev ? (LL-1-li) : li;
    #pragma unroll
    for (int dd=0;dd<4;dd++) u_s[dd][lane] = usrc[ubase + (size_t)dd*LL + lsrc];
    #pragma unroll
    for (int r=0;r<16;r++){
      B_s[r][lane] = xd[(size_t)(RR+r)*LL + li];
      C_s[r][lane] = xd[(size_t)(RR+NN+r)*LL + li];
    }
    float xr[12];
    #pragma unroll
    for (int r=0;r<12;r++) xr[r] = xd[(size_t)r*LL + li];
    #pragma unroll
    for (int dd=0;dd<4;dd++){
      float a = dtb_r[dd];
      #pragma unroll
      for (int r=0;r<12;r++) a = fmaf(xr[r], dtw_r[dd][r], a);
      dt_s[dd][lane] = softplusf_(a);
    }
    __syncthreads();
    #pragma unroll
    for (int j4=0;j4<16;j4++){
      float4 dt4 = *(const float4*)&dt_s[dl][j4*4];
      float4 u4  = *(const float4*)&u_s[dl][j4*4];
      float4 B4  = *(const float4*)&B_s[n][j4*4];
      float4 C4  = *(const float4*)&C_s[n][j4*4];
      float dta[4]={dt4.x,dt4.y,dt4.z,dt4.w};
      float ua[4]={u4.x,u4.y,u4.z,u4.w};
      float Ba[4]={B4.x,B4.y,B4.z,B4.w};
      float Ca[4]={C4.x,C4.y,C4.z,C4.w};
      #pragma unroll
      for (int jj=0;jj<4;jj++){
        float dt = dta[jj], uu = ua[jj];
        float dA = __expf(dt * Acoef);
        h = fmaf(dA, h, dt*uu*Ba[jj]);
        float part = h * Ca[jj];
        part += __shfl_xor(part, 1);
        part += __shfl_xor(part, 2);
        part += __shfl_xor(part, 4);
        part += __shfl_xor(part, 8);
        if (n == 0) y_s[dl][j4*4+jj] = part + uu*Dd;
      }
    }
    __syncthreads();
    #pragma unroll
    for (int dd=0;dd<4;dd++) ys[ysbase + (size_t)dd*LL + lc0 + lane] = y_s[dd][lane];
    __syncthreads();
  }
}

// ---------------- combine 4 directions -> ysum (B,Di,L) ----------------
__global__ void k_combine(const float* __restrict__ ys, float* __restrict__ ysum) {
  __shared__ float t[32][33];
  int bd = blockIdx.x; int b = bd / DI, d = bd % DI;
  int h0 = blockIdx.y*32, w0 = blockIdx.z*32;
  int tx = threadIdx.x, ty = threadIdx.y;
  const float* y0p = ys + ((size_t)((b*KK+0)*DI + d))*LL;
  const float* y1p = ys + ((size_t)((b*KK+1)*DI + d))*LL;
  const float* y2p = ys + ((size_t)((b*KK+2)*DI + d))*LL;
  const float* y3p = ys + ((size_t)((b*KK+3)*DI + d))*LL;
  #pragma unroll
  for (int r=0;r<4;r++){ int wl = ty + r*8; int w = w0+wl; int h = h0+tx;
    if (w < WWW && h < HHH){ int l1 = w*HHH + h;
      t[wl][tx] = y1p[l1] + y3p[LL-1-l1]; } }
  __syncthreads();
  #pragma unroll
  for (int r=0;r<4;r++){ int hl = ty + r*8; int h = h0+hl; int w = w0+tx;
    if (h < HHH && w < WWW){ int l = h*WWW + w;
      ysum[((size_t)(b*DI+d))*LL + l] = t[tx][hl] + y0p[l] + y2p[LL-1-l]; } }
}

// ---------------- per-(b,l) mean/rstd over Di ----------------
__global__ void k_stats(const float* __restrict__ ysum, float* __restrict__ stats) {
  __shared__ float sa[4][64], sb[4][64];
  int b = blockIdx.x, l = blockIdx.y*64 + threadIdx.x;
  int ty = threadIdx.y;
  float s=0.f, s2=0.f;
  for (int dd=ty; dd<DI; dd+=4){
    float v = ysum[((size_t)(b*DI+dd))*LL + l];
    s += v; s2 += v*v;
  }
  sa[ty][threadIdx.x]=s; sb[ty][threadIdx.x]=s2;
  __syncthreads();
  if (ty==0){
    s  = sa[0][threadIdx.x]+sa[1][threadIdx.x]+sa[2][threadIdx.x]+sa[3][threadIdx.x];
    s2 = sb[0][threadIdx.x]+sb[1][threadIdx.x]+sb[2][threadIdx.x]+sb[3][threadIdx.x];
    float m = s*(1.f/DI);
    float var = s2*(1.f/DI) - m*m;
    stats[b*LL + l] = m;
    stats[BL + b*LL + l] = rsqrtf(var + 1e-5f);
  }
}

// ---------------- transpose + LN + silu(z) gate -> a2 (B,L,Di) ----------------
__global__ void k_transLN(const float* __restrict__ ysum, const float* __restrict__ stats,
      const float* __restrict__ og, const float* __restrict__ ob,
      const float* __restrict__ xz, float* __restrict__ a2) {
  __shared__ float t[32][33];
  int b = blockIdx.x, l0 = blockIdx.y*32, d0 = blockIdx.z*32;
  int tx = threadIdx.x, ty = threadIdx.y;
  #pragma unroll
  for (int r=0;r<4;r++){ int dr = ty+r*8;
    t[dr][tx] = ysum[((size_t)(b*DI + d0+dr))*LL + l0+tx]; }
  __syncthreads();
  #pragma unroll
  for (int r=0;r<4;r++){ int lr = ty+r*8; int l = l0+lr; int d = d0+tx;
    float m  = stats[b*LL + l];
    float rs = stats[BL + b*LL + l];
    float v = (t[tx][lr] - m)*rs*og[d] + ob[d];
    float z = xz[((size_t)(b*LL+l))*(2*DI) + DI + d];
    a2[((size_t)(b*LL+l))*DI + d] = v * siluf_(z);
  }
}

extern "C" void kernel_launch(void* const* d_in, const int* in_sizes, int n_in,
                              void* d_out, int out_size, void* d_ws, size_t ws_size,
                              hipStream_t stream) {
  (void)in_sizes; (void)n_in; (void)out_size; (void)ws_size;
  const float* x       = (const float*)d_in[0];
  const float* cpe1_w  = (const float*)d_in[1];
  const float* cpe1_b  = (const float*)d_in[2];
  const float* ln1_g   = (const float*)d_in[3];
  const float* ln1_b   = (const float*)d_in[4];
  const float* in_proj = (const float*)d_in[5];
  const float* conv_w  = (const float*)d_in[6];
  const float* conv_b  = (const float*)d_in[7];
  const float* x_proj  = (const float*)d_in[8];
  const float* dt_w    = (const float*)d_in[9];
  const float* dt_b    = (const float*)d_in[10];
  const float* A_logs  = (const float*)d_in[11];
  const float* Dsv     = (const float*)d_in[12];
  const float* onorm_g = (const float*)d_in[13];
  const float* onorm_b = (const float*)d_in[14];
  const float* out_proj= (const float*)d_in[15];
  const float* cpe2_w  = (const float*)d_in[16];
  const float* cpe2_b  = (const float*)d_in[17];
  const float* ln2_g   = (const float*)d_in[18];
  const float* ln2_b   = (const float*)d_in[19];
  const float* fc1_w   = (const float*)d_in[20];
  const float* fc1_b   = (const float*)d_in[21];
  const float* fc2_w   = (const float*)d_in[22];
  const float* fc2_b   = (const float*)d_in[23];
  float* out = (float*)d_out;
  float* wsf = (float*)d_ws;

  float* x1      = wsf;                    // 1,204,224
  float* xln     = x1 + 1204224;           // 1,204,224
  float* xz      = xln + 1204224;          // 4,816,896
  float* xc_nhwc = xz + 4816896;           // 2,408,448
  float* xc_dl   = xc_nhwc + 2408448;      // 2,408,448
  float* xcT     = xc_dl + 2408448;        // 2,408,448
  float* ysbuf   = xcT + 2408448;          // 9,633,792
  float* ysum    = ysbuf + 9633792;        // 2,408,448
  float* stats   = ysum + 2408448;         // 12,544
  // aliases (lifetime-disjoint)
  float* xdbl = xc_nhwc;   // after transposes
  float* a2   = xc_dl;     // after scan
  float* x2   = xcT;       // after scan
  float* x3   = xz;        // after transLN
  float* hbuf = ysbuf;     // after combine
  float* xln2 = xln;

  k_dwconv_res<<<(BB*HHH*WWW*CC+255)/256, 256, 0, stream>>>(x, cpe1_w, cpe1_b, x1);
  k_ln192<<<BL/4, 256, 0, stream>>>(x1, ln1_g, ln1_b, xln, 1e-6f);
  k_gemm<EPI_NONE><<<dim3(768/64, BL/64), 256, 0, stream>>>(xln, in_proj, nullptr, nullptr, xz, BL, 2*DI, CC);
  k_conv_xx<<<(BB*LL*DI+255)/256, 256, 0, stream>>>(xz, conv_w, conv_b, xc_nhwc);
  k_trans_dl<<<dim3(BB, 98, 12), dim3(32,8), 0, stream>>>(xc_nhwc, xc_dl);
  k_trans_T<<<dim3(BB*WWW, 2, 12), dim3(32,8), 0, stream>>>(xc_nhwc, xcT);
  k_xdbl<<<dim3(BB*KK, 49), dim3(64,4), 0, stream>>>(xc_dl, xcT, x_proj, xdbl);
  k_scan<<<BB*KK*96, 64, 0, stream>>>(xc_dl, xcT, xdbl, dt_w, dt_b, A_logs, Dsv, ysbuf);
  k_combine<<<dim3(BB*DI, 2, 2), dim3(32,8), 0, stream>>>(ysbuf, ysum);
  k_stats<<<dim3(BB, 49), dim3(64,4), 0, stream>>>(ysum, stats);
  k_transLN<<<dim3(BB, 98, 12), dim3(32,8), 0, stream>>>(ysum, stats, onorm_g, onorm_b, xz, a2);
  k_gemm<EPI_RES><<<dim3(CC/64, BL/64), 256, 0, stream>>>(a2, out_proj, nullptr, x1, x2, BL, CC, DI);
  k_dwconv_res<<<(BB*HHH*WWW*CC+255)/256, 256, 0, stream>>>(x2, cpe2_w, cpe2_b, x3);
  k_ln192<<<BL/4, 256, 0, stream>>>(x3, ln2_g, ln2_b, xln2, 1e-6f);
  k_gemm<EPI_BIAS_GELU><<<dim3(HIDN/64, BL/64), 256, 0, stream>>>(xln2, fc1_w, fc1_b, nullptr, hbuf, BL, HIDN, CC);
  k_gemm<EPI_BIAS_RES><<<dim3(CC/64, BL/64), 256, 0, stream>>>(hbuf, fc2_w, fc2_b, x3, out, BL, CC, HIDN);
}

// Round 2
// 471.028 us; speedup vs baseline: 1.8624x; 1.8624x over previous
//
#include <hip/hip_runtime.h>
#include <math.h>

#define BB 2
#define HHH 56
#define WWW 56
#define CC 192
#define LL 3136
#define DI 384
#define KK 4
#define NN 16
#define RR 12
#define CP 44
#define HIDN 768
#define BL (BB*LL)
#define NCH 49   // chunks per sequence
#define CHL 64   // chunk length (49*64 = 3136)

__device__ __forceinline__ float siluf_(float x){ return x/(1.f+__expf(-x)); }
__device__ __forceinline__ float softplusf_(float x){ return fmaxf(x,0.f) + log1pf(__expf(-fabsf(x))); }
__device__ __forceinline__ float geluf_(float x){ return 0.5f*x*(1.f+erff(x*0.70710678118654752f)); }

// sum across the 16 lanes of a DPP row (n = lane&15); all lanes get the sum.
__device__ __forceinline__ float row_red16(float p){
  p += __int_as_float(__builtin_amdgcn_update_dpp(0, __float_as_int(p), 0xB1, 0xF, 0xF, true));  // quad_perm xor1
  p += __int_as_float(__builtin_amdgcn_update_dpp(0, __float_as_int(p), 0x4E, 0xF, 0xF, true));  // quad_perm xor2
  p += __int_as_float(__builtin_amdgcn_update_dpp(0, __float_as_int(p), 0x124, 0xF, 0xF, true)); // row_ror:4
  p += __int_as_float(__builtin_amdgcn_update_dpp(0, __float_as_int(p), 0x128, 0xF, 0xF, true)); // row_ror:8
  return p;
}

// ---------------- depthwise 3x3 + residual (NHWC, C=192) ----------------
__global__ void k_dwconv_res(const float* __restrict__ in, const float* __restrict__ wgt,
                             const float* __restrict__ bias, float* __restrict__ out) {
  int idx = blockIdx.x*256 + threadIdx.x;
  const int total = BB*HHH*WWW*CC;
  if (idx >= total) return;
  int c = idx % CC;
  int w = (idx / CC) % WWW;
  int h = (idx / (CC*WWW)) % HHH;
  int b = idx / (CC*WWW*HHH);
  float acc = bias[c];
  #pragma unroll
  for (int kh=0; kh<3; kh++){
    int hh = h + kh - 1; if (hh < 0 || hh >= HHH) continue;
    #pragma unroll
    for (int kw=0; kw<3; kw++){
      int ww = w + kw - 1; if (ww < 0 || ww >= WWW) continue;
      acc += in[((b*HHH+hh)*WWW+ww)*CC + c] * wgt[c*9 + kh*3 + kw];
    }
  }
  out[idx] = in[idx] + acc;
}

// ---------------- LayerNorm over D=192, one wave per row ----------------
__global__ void k_ln192(const float* __restrict__ in, const float* __restrict__ g,
                        const float* __restrict__ bta, float* __restrict__ out, float eps) {
  int row = blockIdx.x*4 + (threadIdx.x>>6);
  int lane = threadIdx.x & 63;
  const float* p = in + (size_t)row*CC;
  float v0=p[lane], v1=p[lane+64], v2=p[lane+128];
  float s = v0+v1+v2, s2 = v0*v0+v1*v1+v2*v2;
  #pragma unroll
  for (int off=1; off<64; off<<=1){ s += __shfl_xor(s,off); s2 += __shfl_xor(s2,off); }
  float m = s*(1.f/192.f);
  float var = s2*(1.f/192.f) - m*m;
  float rstd = rsqrtf(var + eps);
  float* q = out + (size_t)row*CC;
  q[lane]     = (v0-m)*rstd*g[lane]     + bta[lane];
  q[lane+64]  = (v1-m)*rstd*g[lane+64]  + bta[lane+64];
  q[lane+128] = (v2-m)*rstd*g[lane+128] + bta[lane+128];
}

// ---------------- fp32 GEMM: out(MxN) = A(MxK) * W(NxK)^T, tile 64x64 ----------------
enum { EPI_NONE=0, EPI_RES=1, EPI_BIAS_GELU=2, EPI_BIAS_RES=3 };

template<int EPI>
__global__ __launch_bounds__(256) void k_gemm(const float* __restrict__ A, const float* __restrict__ Wt,
            const float* __restrict__ bias, const float* __restrict__ res,
            float* __restrict__ out, int M, int Nn, int Kk) {
  __shared__ float As[16][68];
  __shared__ float Bs[16][68];
  int tid = threadIdx.x;
  int m0 = blockIdx.y*64, n0 = blockIdx.x*64;
  int tm = tid & 15, tn = tid >> 4;
  int ldr = tid >> 2, ldc = (tid & 3)*4;
  float acc[4][4];
  #pragma unroll
  for (int i=0;i<4;i++)
    #pragma unroll
    for (int j=0;j<4;j++) acc[i][j]=0.f;
  const float* Ap = A  + (size_t)(m0+ldr)*Kk + ldc;
  const float* Wp = Wt + (size_t)(n0+ldr)*Kk + ldc;
  for (int k0=0; k0<Kk; k0+=16) {
    float4 a  = *(const float4*)(Ap + k0);
    float4 bw = *(const float4*)(Wp + k0);
    __syncthreads();
    As[ldc+0][ldr]=a.x;  As[ldc+1][ldr]=a.y;  As[ldc+2][ldr]=a.z;  As[ldc+3][ldr]=a.w;
    Bs[ldc+0][ldr]=bw.x; Bs[ldc+1][ldr]=bw.y; Bs[ldc+2][ldr]=bw.z; Bs[ldc+3][ldr]=bw.w;
    __syncthreads();
    #pragma unroll
    for (int kk=0; kk<16; kk++){
      float4 av = *(const float4*)&As[kk][tm*4];
      float4 bv = *(const float4*)&Bs[kk][tn*4];
      float am[4] = {av.x, av.y, av.z, av.w};
      float bn[4] = {bv.x, bv.y, bv.z, bv.w};
      #pragma unroll
      for (int i=0;i<4;i++)
        #pragma unroll
        for (int j=0;j<4;j++) acc[i][j] = fmaf(am[i], bn[j], acc[i][j]);
    }
  }
  #pragma unroll
  for (int i=0;i<4;i++){
    int m = m0 + tm*4 + i;
    int n = n0 + tn*4;
    float o[4] = {acc[i][0], acc[i][1], acc[i][2], acc[i][3]};
    if (EPI==EPI_BIAS_GELU || EPI==EPI_BIAS_RES){
      const float4 bs = *(const float4*)&bias[n];
      o[0]+=bs.x; o[1]+=bs.y; o[2]+=bs.z; o[3]+=bs.w;
    }
    if (EPI==EPI_BIAS_GELU){
      #pragma unroll
      for (int j=0;j<4;j++) o[j] = geluf_(o[j]);
    }
    if (EPI==EPI_RES || EPI==EPI_BIAS_RES){
      const float4 rv = *(const float4*)&res[(size_t)m*Nn + n];
      o[0]+=rv.x; o[1]+=rv.y; o[2]+=rv.z; o[3]+=rv.w;
    }
    float4 ov = make_float4(o[0],o[1],o[2],o[3]);
    *(float4*)&out[(size_t)m*Nn + n] = ov;
  }
}

// ---------------- depthwise conv 3x3 + bias + SiLU on xx half of xz ----------------
__global__ void k_conv_xx(const float* __restrict__ xz, const float* __restrict__ cw,
                          const float* __restrict__ cb, float* __restrict__ xc) {
  int idx = blockIdx.x*256 + threadIdx.x;
  if (idx >= BB*LL*DI) return;
  int d = idx % DI;
  int l = (idx / DI) % LL;
  int b = idx / (DI*LL);
  int h = l / WWW, w = l % WWW;
  float acc = cb[d];
  #pragma unroll
  for (int kh=0; kh<3; kh++){
    int hh = h + kh - 1; if (hh < 0 || hh >= HHH) continue;
    #pragma unroll
    for (int kw=0; kw<3; kw++){
      int ww2 = w + kw - 1; if (ww2 < 0 || ww2 >= WWW) continue;
      acc += xz[((size_t)(b*LL + hh*WWW + ww2))*(2*DI) + d] * cw[d*9 + kh*3 + kw];
    }
  }
  xc[idx] = siluf_(acc);
}

// ---------------- (B,L,Di) -> (B,Di,L) transpose ----------------
__global__ void k_trans_dl(const float* __restrict__ in, float* __restrict__ out) {
  __shared__ float t[32][33];
  int b = blockIdx.x, l0 = blockIdx.y*32, d0 = blockIdx.z*32;
  int tx = threadIdx.x, ty = threadIdx.y;
  #pragma unroll
  for (int r=0;r<4;r++){ int lr = ty + r*8;
    t[lr][tx] = in[((size_t)(b*LL + l0+lr))*DI + d0 + tx]; }
  __syncthreads();
  #pragma unroll
  for (int r=0;r<4;r++){ int dr = ty + r*8;
    out[((size_t)(b*DI + d0+dr))*LL + l0 + tx] = t[tx][dr]; }
}

// ---------------- (B,L,Di) -> (B,Di,L1) with l1 = w*H + h ----------------
__global__ void k_trans_T(const float* __restrict__ in, float* __restrict__ out) {
  __shared__ float t[32][33];
  int bw = blockIdx.x;
  int b = bw / WWW, w = bw % WWW;
  int h0 = blockIdx.y*32, d0 = blockIdx.z*32;
  int tx = threadIdx.x, ty = threadIdx.y;
  #pragma unroll
  for (int r=0;r<4;r++){ int hr = ty + r*8; int h = h0 + hr;
    if (h < HHH) t[hr][tx] = in[((size_t)(b*LL + h*WWW + w))*DI + d0 + tx]; }
  __syncthreads();
  #pragma unroll
  for (int r=0;r<4;r++){ int dr = ty + r*8; int h = h0 + tx;
    if (h < HHH) out[((size_t)(b*DI + d0+dr))*LL + w*HHH + h] = t[tx][dr]; }
}

// ---------------- x_dbl[b,k,c,l] = sum_d u_k(b,d,l) * xpw[k,c,d] ----------------
__global__ __launch_bounds__(256) void k_xdbl(const float* __restrict__ xc_dl, const float* __restrict__ xcT,
        const float* __restrict__ xpw, float* __restrict__ xdbl) {
  __shared__ float wsm[CP][32];
  int bk = blockIdx.x;
  int b = bk / KK, k = bk % KK;
  int l = blockIdx.y*64 + threadIdx.x;
  int cslot = threadIdx.y;
  const float* usrc = (k & 1) ? xcT : xc_dl;
  int lidx = (k < 2) ? l : (LL-1-l);
  float acc[11];
  #pragma unroll
  for (int j=0;j<11;j++) acc[j]=0.f;
  int tid = threadIdx.y*64 + threadIdx.x;
  for (int d0=0; d0<DI; d0+=32) {
    __syncthreads();
    for (int idx=tid; idx<CP*32; idx+=256) {
      int c = idx >> 5, dd = idx & 31;
      wsm[c][dd] = xpw[(k*CP + c)*DI + d0 + dd];
    }
    __syncthreads();
    #pragma unroll
    for (int dd=0; dd<32; dd++) {
      float u = usrc[((size_t)(b*DI + d0+dd))*LL + lidx];
      #pragma unroll
      for (int j=0;j<11;j++) acc[j] = fmaf(u, wsm[cslot*11+j][dd], acc[j]);
    }
  }
  size_t base = ((size_t)bk*CP)*LL + l;
  #pragma unroll
  for (int j=0;j<11;j++) xdbl[base + (size_t)(cslot*11+j)*LL] = acc[j];
}

// ======== chunked selective scan ========
// S1: per-(b,k,dblk,chunk) wave: local scan from zero -> hend (per d,n), sumdt (per d)
__global__ __launch_bounds__(64) void k_scan1(const float* __restrict__ xc_dl, const float* __restrict__ xcT,
        const float* __restrict__ xdbl, const float* __restrict__ dtw, const float* __restrict__ dtb,
        const float* __restrict__ alogs, float* __restrict__ hend, float* __restrict__ sumdt) {
  __shared__ float dt_s[4][68], u_s[4][68], B_s[16][68];
  int bid = blockIdx.x;
  int ch = bid % NCH;
  int dblk = (bid/NCH) % 96;
  int k = (bid/(NCH*96)) % KK;
  int b = bid/(NCH*96*KK);
  int lane = threadIdx.x;
  int n = lane & 15, dl = lane >> 4;
  int d = dblk*4 + dl;
  float Acoef = -__expf(alogs[(k*DI + d)*NN + n]);
  float dtw_r[4][12]; float dtb_r[4];
  #pragma unroll
  for (int dd=0; dd<4; dd++){
    dtb_r[dd] = dtb[k*DI + dblk*4 + dd];
    #pragma unroll
    for (int r=0;r<12;r++) dtw_r[dd][r] = dtw[(k*DI + dblk*4+dd)*RR + r];
  }
  const float* usrc = (k & 1) ? xcT : xc_dl;
  const float* xd = xdbl + ((size_t)(b*KK + k)*CP)*LL;
  bool rev = (k >= 2);
  size_t ubase = ((size_t)(b*DI + dblk*4))*LL;
  int l0 = ch*CHL;
  int li = l0 + lane;
  int lsrc = rev ? (LL-1-li) : li;
  #pragma unroll
  for (int dd=0;dd<4;dd++) u_s[dd][lane] = usrc[ubase + (size_t)dd*LL + lsrc];
  #pragma unroll
  for (int r=0;r<16;r++) B_s[r][lane] = xd[(size_t)(RR+r)*LL + li];
  float xr[12];
  #pragma unroll
  for (int r=0;r<12;r++) xr[r] = xd[(size_t)r*LL + li];
  #pragma unroll
  for (int dd=0;dd<4;dd++){
    float a = dtb_r[dd];
    #pragma unroll
    for (int r=0;r<12;r++) a = fmaf(xr[r], dtw_r[dd][r], a);
    dt_s[dd][lane] = softplusf_(a);
  }
  __syncthreads();
  float h = 0.f, cum = 0.f;
  #pragma unroll
  for (int j4=0;j4<16;j4++){
    float4 dt4 = *(const float4*)&dt_s[dl][j4*4];
    float4 u4  = *(const float4*)&u_s[dl][j4*4];
    float4 B4  = *(const float4*)&B_s[n][j4*4];
    float dta[4]={dt4.x,dt4.y,dt4.z,dt4.w};
    float ua[4]={u4.x,u4.y,u4.z,u4.w};
    float Ba[4]={B4.x,B4.y,B4.z,B4.w};
    #pragma unroll
    for (int jj=0;jj<4;jj++){
      float dt = dta[jj];
      h = fmaf(__expf(dt*Acoef), h, dt*ua[jj]*Ba[jj]);
      cum += dt;
    }
  }
  hend[(size_t)bid*64 + lane] = h;
  if (n == 0) sumdt[bid*4 + dl] = cum;
}

// S2: per-(b,k,dblk) wave: 49-chunk prefix; rewrite hend[c] in place with INCOMING state H_{c-1}
__global__ __launch_bounds__(64) void k_scanmid(const float* __restrict__ alogs,
        const float* __restrict__ sumdt, float* __restrict__ hend) {
  int bid = blockIdx.x;
  int dblk = bid % 96;
  int k = (bid/96) % KK;
  int b = bid/(96*KK);
  int lane = threadIdx.x;
  int n = lane & 15, dl = lane >> 4;
  int d = dblk*4 + dl;
  float Acoef = -__expf(alogs[(k*DI + d)*NN + n]);
  size_t base = ((size_t)((b*KK + k)*96 + dblk))*NCH;
  float H = 0.f;
  for (int c=0;c<NCH;c++){
    float a = __expf(Acoef * sumdt[(base+c)*4 + dl]);
    size_t idx = (base+c)*64 + lane;
    float tmp = hend[idx];
    hend[idx] = H;
    H = fmaf(a, H, tmp);
  }
}

// S3: per-(b,k,dblk,chunk) wave: full scan with incoming state, compute y, write ys
__global__ __launch_bounds__(64) void k_scan2(const float* __restrict__ xc_dl, const float* __restrict__ xcT,
        const float* __restrict__ xdbl, const float* __restrict__ dtw, const float* __restrict__ dtb,
        const float* __restrict__ alogs, const float* __restrict__ Dsv,
        const float* __restrict__ hend, float* __restrict__ ys) {
  __shared__ float dt_s[4][68], u_s[4][68], B_s[16][68], C_s[16][68], y_s[4][68];
  int bid = blockIdx.x;
  int ch = bid % NCH;
  int dblk = (bid/NCH) % 96;
  int k = (bid/(NCH*96)) % KK;
  int b = bid/(NCH*96*KK);
  int lane = threadIdx.x;
  int n = lane & 15, dl = lane >> 4;
  int d = dblk*4 + dl;
  float Acoef = -__expf(alogs[(k*DI + d)*NN + n]);
  float Dd = Dsv[k*DI + d];
  float dtw_r[4][12]; float dtb_r[4];
  #pragma unroll
  for (int dd=0; dd<4; dd++){
    dtb_r[dd] = dtb[k*DI + dblk*4 + dd];
    #pragma unroll
    for (int r=0;r<12;r++) dtw_r[dd][r] = dtw[(k*DI + dblk*4+dd)*RR + r];
  }
  const float* usrc = (k & 1) ? xcT : xc_dl;
  const float* xd = xdbl + ((size_t)(b*KK + k)*CP)*LL;
  bool rev = (k >= 2);
  size_t ubase  = ((size_t)(b*DI + dblk*4))*LL;
  size_t ysbase = ((size_t)((b*KK + k)*DI + dblk*4))*LL;
  int l0 = ch*CHL;
  int li = l0 + lane;
  int lsrc = rev ? (LL-1-li) : li;
  #pragma unroll
  for (int dd=0;dd<4;dd++) u_s[dd][lane] = usrc[ubase + (size_t)dd*LL + lsrc];
  #pragma unroll
  for (int r=0;r<16;r++){
    B_s[r][lane] = xd[(size_t)(RR+r)*LL + li];
    C_s[r][lane] = xd[(size_t)(RR+NN+r)*LL + li];
  }
  float xr[12];
  #pragma unroll
  for (int r=0;r<12;r++) xr[r] = xd[(size_t)r*LL + li];
  #pragma unroll
  for (int dd=0;dd<4;dd++){
    float a = dtb_r[dd];
    #pragma unroll
    for (int r=0;r<12;r++) a = fmaf(xr[r], dtw_r[dd][r], a);
    dt_s[dd][lane] = softplusf_(a);
  }
  float h = hend[(size_t)bid*64 + lane];   // incoming state H_{c-1}
  __syncthreads();
  #pragma unroll
  for (int j4=0;j4<16;j4++){
    float4 dt4 = *(const float4*)&dt_s[dl][j4*4];
    float4 u4  = *(const float4*)&u_s[dl][j4*4];
    float4 B4  = *(const float4*)&B_s[n][j4*4];
    float4 C4  = *(const float4*)&C_s[n][j4*4];
    float dta[4]={dt4.x,dt4.y,dt4.z,dt4.w};
    float ua[4]={u4.x,u4.y,u4.z,u4.w};
    float Ba[4]={B4.x,B4.y,B4.z,B4.w};
    float Ca[4]={C4.x,C4.y,C4.z,C4.w};
    #pragma unroll
    for (int jj=0;jj<4;jj++){
      float dt = dta[jj], uu = ua[jj];
      h = fmaf(__expf(dt*Acoef), h, dt*uu*Ba[jj]);
      float p = row_red16(h * Ca[jj]);
      if (n == 0) y_s[dl][j4*4+jj] = p + uu*Dd;
    }
  }
  __syncthreads();
  #pragma unroll
  for (int dd=0;dd<4;dd++) ys[ysbase + (size_t)dd*LL + l0 + lane] = y_s[dd][lane];
}

// ---------------- combine 4 directions -> ysum (B,Di,L) ----------------
__global__ void k_combine(const float* __restrict__ ys, float* __restrict__ ysum) {
  __shared__ float t[32][33];
  int bd = blockIdx.x; int b = bd / DI, d = bd % DI;
  int h0 = blockIdx.y*32, w0 = blockIdx.z*32;
  int tx = threadIdx.x, ty = threadIdx.y;
  const float* y0p = ys + ((size_t)((b*KK+0)*DI + d))*LL;
  const float* y1p = ys + ((size_t)((b*KK+1)*DI + d))*LL;
  const float* y2p = ys + ((size_t)((b*KK+2)*DI + d))*LL;
  const float* y3p = ys + ((size_t)((b*KK+3)*DI + d))*LL;
  #pragma unroll
  for (int r=0;r<4;r++){ int wl = ty + r*8; int w = w0+wl; int h = h0+tx;
    if (w < WWW && h < HHH){ int l1 = w*HHH + h;
      t[wl][tx] = y1p[l1] + y3p[LL-1-l1]; } }
  __syncthreads();
  #pragma unroll
  for (int r=0;r<4;r++){ int hl = ty + r*8; int h = h0+hl; int w = w0+tx;
    if (h < HHH && w < WWW){ int l = h*WWW + w;
      ysum[((size_t)(b*DI+d))*LL + l] = t[tx][hl] + y0p[l] + y2p[LL-1-l]; } }
}

// ---------------- per-(b,l) mean/rstd over Di ----------------
__global__ void k_stats(const float* __restrict__ ysum, float* __restrict__ stats) {
  __shared__ float sa[4][64], sb[4][64];
  int b = blockIdx.x, l = blockIdx.y*64 + threadIdx.x;
  int ty = threadIdx.y;
  float s=0.f, s2=0.f;
  for (int dd=ty; dd<DI; dd+=4){
    float v = ysum[((size_t)(b*DI+dd))*LL + l];
    s += v; s2 += v*v;
  }
  sa[ty][threadIdx.x]=s; sb[ty][threadIdx.x]=s2;
  __syncthreads();
  if (ty==0){
    s  = sa[0][threadIdx.x]+sa[1][threadIdx.x]+sa[2][threadIdx.x]+sa[3][threadIdx.x];
    s2 = sb[0][threadIdx.x]+sb[1][threadIdx.x]+sb[2][threadIdx.x]+sb[3][threadIdx.x];
    float m = s*(1.f/DI);
    float var = s2*(1.f/DI) - m*m;
    stats[b*LL + l] = m;
    stats[BL + b*LL + l] = rsqrtf(var + 1e-5f);
  }
}

// ---------------- transpose + LN + silu(z) gate -> a2 (B,L,Di) ----------------
__global__ void k_transLN(const float* __restrict__ ysum, const float* __restrict__ stats,
      const float* __restrict__ og, const float* __restrict__ ob,
      const float* __restrict__ xz, float* __restrict__ a2) {
  __shared__ float t[32][33];
  int b = blockIdx.x, l0 = blockIdx.y*32, d0 = blockIdx.z*32;
  int tx = threadIdx.x, ty = threadIdx.y;
  #pragma unroll
  for (int r=0;r<4;r++){ int dr = ty+r*8;
    t[dr][tx] = ysum[((size_t)(b*DI + d0+dr))*LL + l0+tx]; }
  __syncthreads();
  #pragma unroll
  for (int r=0;r<4;r++){ int lr = ty+r*8; int l = l0+lr; int d = d0+tx;
    float m  = stats[b*LL + l];
    float rs = stats[BL + b*LL + l];
    float v = (t[tx][lr] - m)*rs*og[d] + ob[d];
    float z = xz[((size_t)(b*LL+l))*(2*DI) + DI + d];
    a2[((size_t)(b*LL+l))*DI + d] = v * siluf_(z);
  }
}

extern "C" void kernel_launch(void* const* d_in, const int* in_sizes, int n_in,
                              void* d_out, int out_size, void* d_ws, size_t ws_size,
                              hipStream_t stream) {
  (void)in_sizes; (void)n_in; (void)out_size; (void)ws_size;
  const float* x       = (const float*)d_in[0];
  const float* cpe1_w  = (const float*)d_in[1];
  const float* cpe1_b  = (const float*)d_in[2];
  const float* ln1_g   = (const float*)d_in[3];
  const float* ln1_b   = (const float*)d_in[4];
  const float* in_proj = (const float*)d_in[5];
  const float* conv_w  = (const float*)d_in[6];
  const float* conv_b  = (const float*)d_in[7];
  const float* x_proj  = (const float*)d_in[8];
  const float* dt_w    = (const float*)d_in[9];
  const float* dt_b    = (const float*)d_in[10];
  const float* A_logs  = (const float*)d_in[11];
  const float* Dsv     = (const float*)d_in[12];
  const float* onorm_g = (const float*)d_in[13];
  const float* onorm_b = (const float*)d_in[14];
  const float* out_proj= (const float*)d_in[15];
  const float* cpe2_w  = (const float*)d_in[16];
  const float* cpe2_b  = (const float*)d_in[17];
  const float* ln2_g   = (const float*)d_in[18];
  const float* ln2_b   = (const float*)d_in[19];
  const float* fc1_w   = (const float*)d_in[20];
  const float* fc1_b   = (const float*)d_in[21];
  const float* fc2_w   = (const float*)d_in[22];
  const float* fc2_b   = (const float*)d_in[23];
  float* out = (float*)d_out;
  float* wsf = (float*)d_ws;

  float* x1      = wsf;                    // 1,204,224
  float* xln     = x1 + 1204224;           // 1,204,224
  float* xz      = xln + 1204224;          // 4,816,896
  float* xc_nhwc = xz + 4816896;           // 2,408,448
  float* xc_dl   = xc_nhwc + 2408448;      // 2,408,448
  float* xcT     = xc_dl + 2408448;        // 2,408,448
  float* ysbuf   = xcT + 2408448;          // 9,633,792
  float* ysum    = ysbuf + 9633792;        // 2,408,448
  float* stats   = ysum + 2408448;         // 12,544
  float* sumdt   = stats + 12544;          // 150,528
  // aliases (lifetime-disjoint)
  float* xdbl = xc_nhwc;   // after transposes
  float* hend = ysum;      // scan phase only (2,408,448 exact); combine writes ysum after
  float* a2   = xc_dl;     // after scan
  float* x2   = xcT;       // after scan
  float* x3   = xz;        // after transLN
  float* hbuf = ysbuf;     // after combine
  float* xln2 = xln;

  k_dwconv_res<<<(BB*HHH*WWW*CC+255)/256, 256, 0, stream>>>(x, cpe1_w, cpe1_b, x1);
  k_ln192<<<BL/4, 256, 0, stream>>>(x1, ln1_g, ln1_b, xln, 1e-6f);
  k_gemm<EPI_NONE><<<dim3(768/64, BL/64), 256, 0, stream>>>(xln, in_proj, nullptr, nullptr, xz, BL, 2*DI, CC);
  k_conv_xx<<<(BB*LL*DI+255)/256, 256, 0, stream>>>(xz, conv_w, conv_b, xc_nhwc);
  k_trans_dl<<<dim3(BB, 98, 12), dim3(32,8), 0, stream>>>(xc_nhwc, xc_dl);
  k_trans_T<<<dim3(BB*WWW, 2, 12), dim3(32,8), 0, stream>>>(xc_nhwc, xcT);
  k_xdbl<<<dim3(BB*KK, 49), dim3(64,4), 0, stream>>>(xc_dl, xcT, x_proj, xdbl);
  k_scan1<<<BB*KK*96*NCH, 64, 0, stream>>>(xc_dl, xcT, xdbl, dt_w, dt_b, A_logs, hend, sumdt);
  k_scanmid<<<BB*KK*96, 64, 0, stream>>>(A_logs, sumdt, hend);
  k_scan2<<<BB*KK*96*NCH, 64, 0, stream>>>(xc_dl, xcT, xdbl, dt_w, dt_b, A_logs, Dsv, hend, ysbuf);
  k_combine<<<dim3(BB*DI, 2, 2), dim3(32,8), 0, stream>>>(ysbuf, ysum);
  k_stats<<<dim3(BB, 49), dim3(64,4), 0, stream>>>(ysum, stats);
  k_transLN<<<dim3(BB, 98, 12), dim3(32,8), 0, stream>>>(ysum, stats, onorm_g, onorm_b, xz, a2);
  k_gemm<EPI_RES><<<dim3(CC/64, BL/64), 256, 0, stream>>>(a2, out_proj, nullptr, x1, x2, BL, CC, DI);
  k_dwconv_res<<<(BB*HHH*WWW*CC+255)/256, 256, 0, stream>>>(x2, cpe2_w, cpe2_b, x3);
  k_ln192<<<BL/4, 256, 0, stream>>>(x3, ln2_g, ln2_b, xln2, 1e-6f);
  k_gemm<EPI_BIAS_GELU><<<dim3(HIDN/64, BL/64), 256, 0, stream>>>(xln2, fc1_w, fc1_b, nullptr, hbuf, BL, HIDN, CC);
  k_gemm<EPI_BIAS_RES><<<dim3(CC/64, BL/64), 256, 0, stream>>>(hbuf, fc2_w, fc2_b, x3, out, BL, CC, HIDN);
}

// Round 3
// 406.728 us; speedup vs baseline: 2.1569x; 1.1581x over previous
//
#include <hip/hip_runtime.h>
#include <math.h>

#define BB 2
#define HHH 56
#define WWW 56
#define CC 192
#define LL 3136
#define DI 384
#define KK 4
#define NN 16
#define RR 12
#define CP 44
#define HIDN 768
#define BL (BB*LL)
#define NCH 49   // chunks per sequence
#define CHL 64   // chunk length (49*64 = 3136)

typedef unsigned short ushort_;
typedef __attribute__((ext_vector_type(8))) short bf16x8;
typedef __attribute__((ext_vector_type(4))) float f32x4;

__device__ __forceinline__ float siluf_(float x){ return x/(1.f+__expf(-x)); }
__device__ __forceinline__ float geluf_(float x){ return 0.5f*x*(1.f+erff(x*0.70710678118654752f)); }
__device__ __forceinline__ unsigned short bf16r_(float x){
  unsigned int u = __float_as_uint(x);
  u += 0x7FFFu + ((u>>16)&1u);
  return (unsigned short)(u>>16);
}

// ---------------- weight fp32 -> bf16 convert (4 segments) ----------------
__global__ void k_cvtw(const float* __restrict__ s0, const float* __restrict__ s1,
                       const float* __restrict__ s2, const float* __restrict__ s3,
                       unsigned short* __restrict__ dst){
  int i = blockIdx.x*256 + threadIdx.x;
  if      (i < 147456) dst[i] = bf16r_(s0[i]);
  else if (i < 221184) dst[i] = bf16r_(s1[i-147456]);
  else if (i < 368640) dst[i] = bf16r_(s2[i-221184]);
  else if (i < 516096) dst[i] = bf16r_(s3[i-368640]);
}

// ---------------- depthwise 3x3 + residual (NHWC, C=192) ----------------
__global__ void k_dwconv_res(const float* __restrict__ in, const float* __restrict__ wgt,
                             const float* __restrict__ bias, float* __restrict__ out) {
  int idx = blockIdx.x*256 + threadIdx.x;
  const int total = BB*HHH*WWW*CC;
  if (idx >= total) return;
  int c = idx % CC;
  int w = (idx / CC) % WWW;
  int h = (idx / (CC*WWW)) % HHH;
  int b = idx / (CC*WWW*HHH);
  float acc = bias[c];
  #pragma unroll
  for (int kh=0; kh<3; kh++){
    int hh = h + kh - 1; if (hh < 0 || hh >= HHH) continue;
    #pragma unroll
    for (int kw=0; kw<3; kw++){
      int ww = w + kw - 1; if (ww < 0 || ww >= WWW) continue;
      acc += in[((b*HHH+hh)*WWW+ww)*CC + c] * wgt[c*9 + kh*3 + kw];
    }
  }
  out[idx] = in[idx] + acc;
}

// ---------------- LayerNorm over D=192, one wave per row, bf16 out ----------------
__global__ void k_ln192(const float* __restrict__ in, const float* __restrict__ g,
                        const float* __restrict__ bta, unsigned short* __restrict__ out, float eps) {
  int row = blockIdx.x*4 + (threadIdx.x>>6);
  int lane = threadIdx.x & 63;
  const float* p = in + (size_t)row*CC;
  float v0=p[lane], v1=p[lane+64], v2=p[lane+128];
  float s = v0+v1+v2, s2 = v0*v0+v1*v1+v2*v2;
  #pragma unroll
  for (int off=1; off<64; off<<=1){ s += __shfl_xor(s,off); s2 += __shfl_xor(s2,off); }
  float m = s*(1.f/192.f);
  float var = s2*(1.f/192.f) - m*m;
  float rstd = rsqrtf(var + eps);
  unsigned short* q = out + (size_t)row*CC;
  q[lane]     = bf16r_((v0-m)*rstd*g[lane]     + bta[lane]);
  q[lane+64]  = bf16r_((v1-m)*rstd*g[lane+64]  + bta[lane+64]);
  q[lane+128] = bf16r_((v2-m)*rstd*g[lane+128] + bta[lane+128]);
}

// ---------------- bf16 MFMA GEMM: out(MxN) = A(MxK) * W(NxK)^T ----------------
enum { EPI_NONE=0, EPI_RES=1, EPI_BIAS_GELU=2, EPI_BIAS_RES=3 };

template<int EPI, int OUTBF>
__global__ __launch_bounds__(256) void k_gemm_mfma(const unsigned short* __restrict__ A,
      const unsigned short* __restrict__ W, const float* __restrict__ bias,
      const float* __restrict__ res, void* __restrict__ outp, int M, int Nn, int Kk) {
  __shared__ unsigned short As[128][40];
  __shared__ unsigned short Bs[64][40];
  int tid = threadIdx.x;
  int m0 = blockIdx.y*128, n0 = blockIdx.x*64;
  int wid = tid>>6, lane = tid&63;
  int wm = wid*32;
  int fr = lane&15, fk = (lane>>4)*8;
  f32x4 acc[2][4];
  #pragma unroll
  for (int i=0;i<2;i++)
    #pragma unroll
    for (int j=0;j<4;j++) acc[i][j] = (f32x4){0.f,0.f,0.f,0.f};
  int arow = tid>>1, ak = (tid&1)*16;
  int wrow = tid>>2, wk = (tid&3)*8;
  const unsigned short* Ap = A + (size_t)(m0+arow)*Kk + ak;
  const unsigned short* Wp = W + (size_t)(n0+wrow)*Kk + wk;
  for (int k0=0; k0<Kk; k0+=32){
    __syncthreads();
    uint4 av0 = *(const uint4*)(Ap + k0);
    uint4 av1 = *(const uint4*)(Ap + k0 + 8);
    uint4 wv  = *(const uint4*)(Wp + k0);
    *(uint4*)&As[arow][ak]   = av0;
    *(uint4*)&As[arow][ak+8] = av1;
    *(uint4*)&Bs[wrow][wk]   = wv;
    __syncthreads();
    bf16x8 af[2], bfr[4];
    #pragma unroll
    for (int mi=0;mi<2;mi++) af[mi] = *(const bf16x8*)&As[wm + mi*16 + fr][fk];
    #pragma unroll
    for (int ni=0;ni<4;ni++) bfr[ni] = *(const bf16x8*)&Bs[ni*16 + fr][fk];
    #pragma unroll
    for (int mi=0;mi<2;mi++)
      #pragma unroll
      for (int ni=0;ni<4;ni++)
        acc[mi][ni] = __builtin_amdgcn_mfma_f32_16x16x32_bf16(af[mi], bfr[ni], acc[mi][ni], 0,0,0);
  }
  int rbase = (lane>>4)*4;
  #pragma unroll
  for (int mi=0;mi<2;mi++){
    #pragma unroll
    for (int ni=0;ni<4;ni++){
      int col = n0 + ni*16 + fr;
      float bv = (EPI==EPI_BIAS_GELU || EPI==EPI_BIAS_RES) ? bias[col] : 0.f;
      #pragma unroll
      for (int r=0;r<4;r++){
        int row = m0 + wm + mi*16 + rbase + r;
        float v = acc[mi][ni][r] + bv;
        if (EPI==EPI_BIAS_GELU) v = geluf_(v);
        if (EPI==EPI_RES || EPI==EPI_BIAS_RES) v += res[(size_t)row*Nn + col];
        if (OUTBF) ((unsigned short*)outp)[(size_t)row*Nn + col] = bf16r_(v);
        else       ((float*)outp)[(size_t)row*Nn + col] = v;
      }
    }
  }
}

// ---------------- depthwise conv 3x3 + bias + SiLU on xx half of xz ----------------
__global__ void k_conv_xx(const float* __restrict__ xz, const float* __restrict__ cw,
                          const float* __restrict__ cb, float* __restrict__ xc) {
  int idx = blockIdx.x*256 + threadIdx.x;
  if (idx >= BB*LL*DI) return;
  int d = idx % DI;
  int l = (idx / DI) % LL;
  int b = idx / (DI*LL);
  int h = l / WWW, w = l % WWW;
  float acc = cb[d];
  #pragma unroll
  for (int kh=0; kh<3; kh++){
    int hh = h + kh - 1; if (hh < 0 || hh >= HHH) continue;
    #pragma unroll
    for (int kw=0; kw<3; kw++){
      int ww2 = w + kw - 1; if (ww2 < 0 || ww2 >= WWW) continue;
      acc += xz[((size_t)(b*LL + hh*WWW + ww2))*(2*DI) + d] * cw[d*9 + kh*3 + kw];
    }
  }
  xc[idx] = siluf_(acc);
}

// ---------------- (B,L,Di) -> (B,Di,L) transpose ----------------
__global__ void k_trans_dl(const float* __restrict__ in, float* __restrict__ out) {
  __shared__ float t[32][33];
  int b = blockIdx.x, l0 = blockIdx.y*32, d0 = blockIdx.z*32;
  int tx = threadIdx.x, ty = threadIdx.y;
  #pragma unroll
  for (int r=0;r<4;r++){ int lr = ty + r*8;
    t[lr][tx] = in[((size_t)(b*LL + l0+lr))*DI + d0 + tx]; }
  __syncthreads();
  #pragma unroll
  for (int r=0;r<4;r++){ int dr = ty + r*8;
    out[((size_t)(b*DI + d0+dr))*LL + l0 + tx] = t[tx][dr]; }
}

// ---------------- (B,L,Di) -> (B,Di,L1) with l1 = w*H + h ----------------
__global__ void k_trans_T(const float* __restrict__ in, float* __restrict__ out) {
  __shared__ float t[32][33];
  int bw = blockIdx.x;
  int b = bw / WWW, w = bw % WWW;
  int h0 = blockIdx.y*32, d0 = blockIdx.z*32;
  int tx = threadIdx.x, ty = threadIdx.y;
  #pragma unroll
  for (int r=0;r<4;r++){ int hr = ty + r*8; int h = h0 + hr;
    if (h < HHH) t[hr][tx] = in[((size_t)(b*LL + h*WWW + w))*DI + d0 + tx]; }
  __syncthreads();
  #pragma unroll
  for (int r=0;r<4;r++){ int dr = ty + r*8; int h = h0 + tx;
    if (h < HHH) out[((size_t)(b*DI + d0+dr))*LL + w*HHH + h] = t[tx][dr]; }
}

// -------- x_dbl records: xdblT[(bk*L + l)*48]: [0:12]=dts_raw, [16:32]=B, [32:48]=C --------
__global__ __launch_bounds__(256) void k_xdbl(const float* __restrict__ xc_dl, const float* __restrict__ xcT,
        const float* __restrict__ xpw, float* __restrict__ xdblT) {
  __shared__ float wsm[CP][32];
  int bk = blockIdx.x;
  int b = bk / KK, k = bk % KK;
  int l = blockIdx.y*64 + threadIdx.x;
  int cslot = threadIdx.y;
  const float* usrc = (k & 1) ? xcT : xc_dl;
  int lidx = (k < 2) ? l : (LL-1-l);
  float acc[11];
  #pragma unroll
  for (int j=0;j<11;j++) acc[j]=0.f;
  int tid = threadIdx.y*64 + threadIdx.x;
  for (int d0=0; d0<DI; d0+=32) {
    __syncthreads();
    for (int idx=tid; idx<CP*32; idx+=256) {
      int c = idx >> 5, dd = idx & 31;
      wsm[c][dd] = xpw[(k*CP + c)*DI + d0 + dd];
    }
    __syncthreads();
    #pragma unroll
    for (int dd=0; dd<32; dd++) {
      float u = usrc[((size_t)(b*DI + d0+dd))*LL + lidx];
      #pragma unroll
      for (int j=0;j<11;j++) acc[j] = fmaf(u, wsm[cslot*11+j][dd], acc[j]);
    }
  }
  size_t base = ((size_t)bk*LL + l)*48;
  #pragma unroll
  for (int j=0;j<11;j++){
    int c = cslot*11 + j;
    int off = (c < 12) ? c : (c + 4);
    xdblT[base + off] = acc[j];
  }
}

// ======== chunked selective scan, d-per-lane layout ========
// S1: block = 384 thr (6 waves), one (b,k,chunk); lane d owns h[16]
__global__ __launch_bounds__(384) void k_scan1(const float* __restrict__ xc_dl, const float* __restrict__ xcT,
        const float* __restrict__ xdblT, const float* __restrict__ dtw, const float* __restrict__ dtb,
        const float* __restrict__ alogs, float* __restrict__ hend, float* __restrict__ sumdt) {
  int bid = blockIdx.x;
  int ch = bid % NCH;
  int k  = (bid/NCH) % KK;
  int b  = bid/(NCH*KK);
  int d  = threadIdx.x;
  int kd = k*DI + d;
  int bk = b*KK + k;
  float w[12];
  #pragma unroll
  for (int r=0;r<12;r++) w[r] = dtw[kd*12 + r];
  float biasd = dtb[kd];
  float An2[16];
  #pragma unroll
  for (int n=0;n<16;n++) An2[n] = -__expf(alogs[kd*16 + n]) * 1.44269504f;
  const float* usrc = (k & 1) ? xcT : xc_dl;
  bool rev = (k >= 2);
  size_t ubase = ((size_t)(b*DI) + d)*LL;
  const float* rec0 = xdblT + ((size_t)bk*LL + ch*CHL)*48;
  float h[16];
  #pragma unroll
  for (int n=0;n<16;n++) h[n]=0.f;
  float cum = 0.f;
  for (int j4=0;j4<16;j4++){
    int li0 = ch*CHL + j4*4;
    float4 u4 = rev ? *(const float4*)&usrc[ubase + (LL-4-li0)]
                    : *(const float4*)&usrc[ubase + li0];
    float ua[4] = {u4.x,u4.y,u4.z,u4.w};
    #pragma unroll
    for (int i=0;i<4;i++){
      const float* rec = rec0 + (size_t)(j4*4+i)*48;
      float a = biasd;
      #pragma unroll
      for (int r=0;r<12;r++) a = fmaf(rec[r], w[r], a);
      float dt = 0.69314718f * log2f(1.f + exp2f(a*1.44269504f));
      float uu = rev ? ua[3-i] : ua[i];
      float dtu = dt*uu;
      cum += dt;
      #pragma unroll
      for (int n=0;n<16;n++){
        float dA = exp2f(dt*An2[n]);
        h[n] = fmaf(dA, h[n], dtu*rec[16+n]);
      }
    }
  }
  size_t hb = ((size_t)(bk*NCH + ch)*DI + d)*16;
  #pragma unroll
  for (int n4=0;n4<4;n4++)
    *(float4*)&hend[hb + n4*4] = make_float4(h[n4*4],h[n4*4+1],h[n4*4+2],h[n4*4+3]);
  sumdt[(bk*NCH + ch)*DI + d] = cum;
}

// S2: per (b,k,4d-block) wave: prefix over chunks; hend[c] <- incoming state H_{c-1}
__global__ __launch_bounds__(64) void k_scanmid(const float* __restrict__ alogs,
        const float* __restrict__ sumdt, float* __restrict__ hend) {
  int bid = blockIdx.x;
  int dblk = bid % 96;
  int k = (bid/96) % KK;
  int b = bid/(96*KK);
  int lane = threadIdx.x;
  int d4 = lane>>4, n = lane&15;
  int d = dblk*4 + d4;
  int bk = b*KK + k;
  float Ac2 = -__expf(alogs[(k*DI+d)*16 + n]) * 1.44269504f;
  float H = 0.f;
  for (int c=0;c<NCH;c++){
    float sdt = sumdt[(bk*NCH + c)*DI + d];
    float aexp = exp2f(Ac2 * sdt);
    size_t idx = ((size_t)(bk*NCH + c)*DI + dblk*4)*16 + lane;
    float tmp = hend[idx];
    hend[idx] = H;
    H = fmaf(aexp, H, tmp);
  }
}

// S3: same as S1 + y computation, starting from incoming state
__global__ __launch_bounds__(384) void k_scan2(const float* __restrict__ xc_dl, const float* __restrict__ xcT,
        const float* __restrict__ xdblT, const float* __restrict__ dtw, const float* __restrict__ dtb,
        const float* __restrict__ alogs, const float* __restrict__ Dsv,
        const float* __restrict__ hend, float* __restrict__ ys) {
  int bid = blockIdx.x;
  int ch = bid % NCH;
  int k  = (bid/NCH) % KK;
  int b  = bid/(NCH*KK);
  int d  = threadIdx.x;
  int kd = k*DI + d;
  int bk = b*KK + k;
  float w[12];
  #pragma unroll
  for (int r=0;r<12;r++) w[r] = dtw[kd*12 + r];
  float biasd = dtb[kd];
  float Dd = Dsv[kd];
  float An2[16];
  #pragma unroll
  for (int n=0;n<16;n++) An2[n] = -__expf(alogs[kd*16 + n]) * 1.44269504f;
  const float* usrc = (k & 1) ? xcT : xc_dl;
  bool rev = (k >= 2);
  size_t ubase = ((size_t)(b*DI) + d)*LL;
  const float* rec0 = xdblT + ((size_t)bk*LL + ch*CHL)*48;
  float h[16];
  size_t hb = ((size_t)(bk*NCH + ch)*DI + d)*16;
  #pragma unroll
  for (int n4=0;n4<4;n4++){
    float4 hv = *(const float4*)&hend[hb + n4*4];
    h[n4*4]=hv.x; h[n4*4+1]=hv.y; h[n4*4+2]=hv.z; h[n4*4+3]=hv.w;
  }
  size_t ysbase = ((size_t)bk*DI + d)*LL + ch*CHL;
  for (int j4=0;j4<16;j4++){
    int li0 = ch*CHL + j4*4;
    float4 u4 = rev ? *(const float4*)&usrc[ubase + (LL-4-li0)]
                    : *(const float4*)&usrc[ubase + li0];
    float ua[4] = {u4.x,u4.y,u4.z,u4.w};
    float ya[4];
    #pragma unroll
    for (int i=0;i<4;i++){
      const float* rec = rec0 + (size_t)(j4*4+i)*48;
      float a = biasd;
      #pragma unroll
      for (int r=0;r<12;r++) a = fmaf(rec[r], w[r], a);
      float dt = 0.69314718f * log2f(1.f + exp2f(a*1.44269504f));
      float uu = rev ? ua[3-i] : ua[i];
      float dtu = dt*uu;
      float y = uu*Dd;
      #pragma unroll
      for (int n=0;n<16;n++){
        float dA = exp2f(dt*An2[n]);
        h[n] = fmaf(dA, h[n], dtu*rec[16+n]);
        y = fmaf(h[n], rec[32+n], y);
      }
      ya[i] = y;
    }
    *(float4*)&ys[ysbase + j4*4] = make_float4(ya[0],ya[1],ya[2],ya[3]);
  }
}

// ---------------- combine 4 directions -> ysum (B,Di,L) ----------------
__global__ void k_combine(const float* __restrict__ ys, float* __restrict__ ysum) {
  __shared__ float t[32][33];
  int bd = blockIdx.x; int b = bd / DI, d = bd % DI;
  int h0 = blockIdx.y*32, w0 = blockIdx.z*32;
  int tx = threadIdx.x, ty = threadIdx.y;
  const float* y0p = ys + ((size_t)((b*KK+0)*DI + d))*LL;
  const float* y1p = ys + ((size_t)((b*KK+1)*DI + d))*LL;
  const float* y2p = ys + ((size_t)((b*KK+2)*DI + d))*LL;
  const float* y3p = ys + ((size_t)((b*KK+3)*DI + d))*LL;
  #pragma unroll
  for (int r=0;r<4;r++){ int wl = ty + r*8; int w = w0+wl; int h = h0+tx;
    if (w < WWW && h < HHH){ int l1 = w*HHH + h;
      t[wl][tx] = y1p[l1] + y3p[LL-1-l1]; } }
  __syncthreads();
  #pragma unroll
  for (int r=0;r<4;r++){ int hl = ty + r*8; int h = h0+hl; int w = w0+tx;
    if (h < HHH && w < WWW){ int l = h*WWW + w;
      ysum[((size_t)(b*DI+d))*LL + l] = t[tx][hl] + y0p[l] + y2p[LL-1-l]; } }
}

// ---------------- per-(b,l) mean/rstd over Di ----------------
__global__ void k_stats(const float* __restrict__ ysum, float* __restrict__ stats) {
  __shared__ float sa[4][64], sb[4][64];
  int b = blockIdx.x, l = blockIdx.y*64 + threadIdx.x;
  int ty = threadIdx.y;
  float s=0.f, s2=0.f;
  for (int dd=ty; dd<DI; dd+=4){
    float v = ysum[((size_t)(b*DI+dd))*LL + l];
    s += v; s2 += v*v;
  }
  sa[ty][threadIdx.x]=s; sb[ty][threadIdx.x]=s2;
  __syncthreads();
  if (ty==0){
    s  = sa[0][threadIdx.x]+sa[1][threadIdx.x]+sa[2][threadIdx.x]+sa[3][threadIdx.x];
    s2 = sb[0][threadIdx.x]+sb[1][threadIdx.x]+sb[2][threadIdx.x]+sb[3][threadIdx.x];
    float m = s*(1.f/DI);
    float var = s2*(1.f/DI) - m*m;
    stats[b*LL + l] = m;
    stats[BL + b*LL + l] = rsqrtf(var + 1e-5f);
  }
}

// ---------------- transpose + LN + silu(z) gate -> a2 (B,L,Di) bf16 ----------------
__global__ void k_transLN(const float* __restrict__ ysum, const float* __restrict__ stats,
      const float* __restrict__ og, const float* __restrict__ ob,
      const float* __restrict__ xz, unsigned short* __restrict__ a2) {
  __shared__ float t[32][33];
  int b = blockIdx.x, l0 = blockIdx.y*32, d0 = blockIdx.z*32;
  int tx = threadIdx.x, ty = threadIdx.y;
  #pragma unroll
  for (int r=0;r<4;r++){ int dr = ty+r*8;
    t[dr][tx] = ysum[((size_t)(b*DI + d0+dr))*LL + l0+tx]; }
  __syncthreads();
  #pragma unroll
  for (int r=0;r<4;r++){ int lr = ty+r*8; int l = l0+lr; int d = d0+tx;
    float m  = stats[b*LL + l];
    float rs = stats[BL + b*LL + l];
    float v = (t[tx][lr] - m)*rs*og[d] + ob[d];
    float z = xz[((size_t)(b*LL+l))*(2*DI) + DI + d];
    a2[((size_t)(b*LL+l))*DI + d] = bf16r_(v * siluf_(z));
  }
}

extern "C" void kernel_launch(void* const* d_in, const int* in_sizes, int n_in,
                              void* d_out, int out_size, void* d_ws, size_t ws_size,
                              hipStream_t stream) {
  (void)in_sizes; (void)n_in; (void)out_size; (void)ws_size;
  const float* x       = (const float*)d_in[0];
  const float* cpe1_w  = (const float*)d_in[1];
  const float* cpe1_b  = (const float*)d_in[2];
  const float* ln1_g   = (const float*)d_in[3];
  const float* ln1_b   = (const float*)d_in[4];
  const float* in_proj = (const float*)d_in[5];
  const float* conv_w  = (const float*)d_in[6];
  const float* conv_b  = (const float*)d_in[7];
  const float* x_proj  = (const float*)d_in[8];
  const float* dt_w    = (const float*)d_in[9];
  const float* dt_b    = (const float*)d_in[10];
  const float* A_logs  = (const float*)d_in[11];
  const float* Dsv     = (const float*)d_in[12];
  const float* onorm_g = (const float*)d_in[13];
  const float* onorm_b = (const float*)d_in[14];
  const float* out_proj= (const float*)d_in[15];
  const float* cpe2_w  = (const float*)d_in[16];
  const float* cpe2_b  = (const float*)d_in[17];
  const float* ln2_g   = (const float*)d_in[18];
  const float* ln2_b   = (const float*)d_in[19];
  const float* fc1_w   = (const float*)d_in[20];
  const float* fc1_b   = (const float*)d_in[21];
  const float* fc2_w   = (const float*)d_in[22];
  const float* fc2_b   = (const float*)d_in[23];
  float* out = (float*)d_out;
  float* wsf = (float*)d_ws;

  float* x1      = wsf;                    // 1,204,224 f
  float* xlnf    = x1 + 1204224;           // 1,204,224 f (bf16 area)
  float* xz      = xlnf + 1204224;         // 4,816,896 f
  float* xc_nhwc = xz + 4816896;           // 2,408,448 f
  float* xc_dl   = xc_nhwc + 2408448;      // 2,408,448 f
  float* xcT     = xc_dl + 2408448;        // 2,408,448 f
  float* ysbuf   = xcT + 2408448;          // 9,633,792 f
  float* ysum    = ysbuf + 9633792;        // 2,408,448 f
  float* stats   = ysum + 2408448;         // 12,544 f (x2)
  float* sumdt   = stats + 12544*2;        // 150,528 f
  unsigned short* wbf = (unsigned short*)(sumdt + 150528);  // 516,096 ushorts
  // aliases (lifetime-disjoint)
  unsigned short* xln  = (unsigned short*)xlnf;   // bf16 LN1 out (feeds in_proj)
  unsigned short* xln2 = (unsigned short*)xlnf;   // bf16 LN2 out (feeds fc1)
  float* xdblT = xc_nhwc;                         // 1,204,224 f, after transposes
  float* hend  = ysum;                            // scan phase (2,408,448 exact)
  unsigned short* a2 = (unsigned short*)xc_dl;    // bf16, after scan
  float* x2   = xcT;                              // fp32, after scan
  float* x3   = xz;                               // fp32, after transLN
  unsigned short* hbuf = (unsigned short*)ysbuf;  // bf16, after combine
  unsigned short* wIn  = wbf;                     // 147456
  unsigned short* wOut = wbf + 147456;            // 73728
  unsigned short* wF1  = wbf + 221184;            // 147456
  unsigned short* wF2  = wbf + 368640;            // 147456

  k_cvtw<<<2016, 256, 0, stream>>>(in_proj, out_proj, fc1_w, fc2_w, wbf);
  k_dwconv_res<<<(BB*HHH*WWW*CC+255)/256, 256, 0, stream>>>(x, cpe1_w, cpe1_b, x1);
  k_ln192<<<BL/4, 256, 0, stream>>>(x1, ln1_g, ln1_b, xln, 1e-6f);
  k_gemm_mfma<EPI_NONE,0><<<dim3(768/64, BL/128), 256, 0, stream>>>(xln, wIn, nullptr, nullptr, xz, BL, 2*DI, CC);
  k_conv_xx<<<(BB*LL*DI+255)/256, 256, 0, stream>>>(xz, conv_w, conv_b, xc_nhwc);
  k_trans_dl<<<dim3(BB, 98, 12), dim3(32,8), 0, stream>>>(xc_nhwc, xc_dl);
  k_trans_T<<<dim3(BB*WWW, 2, 12), dim3(32,8), 0, stream>>>(xc_nhwc, xcT);
  k_xdbl<<<dim3(BB*KK, 49), dim3(64,4), 0, stream>>>(xc_dl, xcT, x_proj, xdblT);
  k_scan1<<<BB*KK*NCH, 384, 0, stream>>>(xc_dl, xcT, xdblT, dt_w, dt_b, A_logs, hend, sumdt);
  k_scanmid<<<BB*KK*96, 64, 0, stream>>>(A_logs, sumdt, hend);
  k_scan2<<<BB*KK*NCH, 384, 0, stream>>>(xc_dl, xcT, xdblT, dt_w, dt_b, A_logs, Dsv, hend, ysbuf);
  k_combine<<<dim3(BB*DI, 2, 2), dim3(32,8), 0, stream>>>(ysbuf, ysum);
  k_stats<<<dim3(BB, 49), dim3(64,4), 0, stream>>>(ysum, stats);
  k_transLN<<<dim3(BB, 98, 12), dim3(32,8), 0, stream>>>(ysum, stats, onorm_g, onorm_b, xz, a2);
  k_gemm_mfma<EPI_RES,0><<<dim3(192/64, BL/128), 256, 0, stream>>>(a2, wOut, nullptr, x1, x2, BL, CC, DI);
  k_dwconv_res<<<(BB*HHH*WWW*CC+255)/256, 256, 0, stream>>>(x2, cpe2_w, cpe2_b, x3);
  k_ln192<<<BL/4, 256, 0, stream>>>(x3, ln2_g, ln2_b, xln2, 1e-6f);
  k_gemm_mfma<EPI_BIAS_GELU,1><<<dim3(768/64, BL/128), 256, 0, stream>>>(xln2, wF1, fc1_b, nullptr, hbuf, BL, HIDN, CC);
  k_gemm_mfma<EPI_BIAS_RES,0><<<dim3(192/64, BL/128), 256, 0, stream>>>(hbuf, wF2, fc2_b, x3, out, BL, CC, HIDN);
}

// Round 4
// 356.596 us; speedup vs baseline: 2.4601x; 1.1406x over previous
//
#include <hip/hip_runtime.h>
#include <math.h>

#define BB 2
#define HHH 56
#define WWW 56
#define CC 192
#define LL 3136
#define DI 384
#define KK 4
#define NN 16
#define RR 12
#define CP 44
#define HIDN 768
#define BL (BB*LL)
#define NCH 98   // chunks per sequence
#define CHL 32   // chunk length (98*32 = 3136)

typedef __attribute__((ext_vector_type(8))) short bf16x8;
typedef __attribute__((ext_vector_type(4))) float f32x4;

__device__ __forceinline__ float siluf_(float x){ return x/(1.f+__expf(-x)); }
__device__ __forceinline__ float geluf_(float x){ return 0.5f*x*(1.f+erff(x*0.70710678118654752f)); }
__device__ __forceinline__ unsigned short bf16r_(float x){
  unsigned int u = __float_as_uint(x);
  u += 0x7FFFu + ((u>>16)&1u);
  return (unsigned short)(u>>16);
}
__device__ __forceinline__ float bf2f_(unsigned short u){
  return __uint_as_float(((unsigned int)u)<<16);
}

// ---------------- weight fp32 -> bf16 convert (4 segments) ----------------
__global__ void k_cvtw(const float* __restrict__ s0, const float* __restrict__ s1,
                       const float* __restrict__ s2, const float* __restrict__ s3,
                       unsigned short* __restrict__ dst){
  int i = blockIdx.x*256 + threadIdx.x;
  if      (i < 147456) dst[i] = bf16r_(s0[i]);
  else if (i < 221184) dst[i] = bf16r_(s1[i-147456]);
  else if (i < 368640) dst[i] = bf16r_(s2[i-221184]);
  else if (i < 516096) dst[i] = bf16r_(s3[i-368640]);
}

// ---------------- depthwise 3x3 + residual (NHWC, C=192) ----------------
__global__ void k_dwconv_res(const float* __restrict__ in, const float* __restrict__ wgt,
                             const float* __restrict__ bias, float* __restrict__ out) {
  int idx = blockIdx.x*256 + threadIdx.x;
  const int total = BB*HHH*WWW*CC;
  if (idx >= total) return;
  int c = idx % CC;
  int w = (idx / CC) % WWW;
  int h = (idx / (CC*WWW)) % HHH;
  int b = idx / (CC*WWW*HHH);
  float acc = bias[c];
  #pragma unroll
  for (int kh=0; kh<3; kh++){
    int hh = h + kh - 1; if (hh < 0 || hh >= HHH) continue;
    #pragma unroll
    for (int kw=0; kw<3; kw++){
      int ww = w + kw - 1; if (ww < 0 || ww >= WWW) continue;
      acc += in[((b*HHH+hh)*WWW+ww)*CC + c] * wgt[c*9 + kh*3 + kw];
    }
  }
  out[idx] = in[idx] + acc;
}

// ---------------- LayerNorm over D=192, one wave per row, bf16 out ----------------
__global__ void k_ln192(const float* __restrict__ in, const float* __restrict__ g,
                        const float* __restrict__ bta, unsigned short* __restrict__ out, float eps) {
  int row = blockIdx.x*4 + (threadIdx.x>>6);
  int lane = threadIdx.x & 63;
  const float* p = in + (size_t)row*CC;
  float v0=p[lane], v1=p[lane+64], v2=p[lane+128];
  float s = v0+v1+v2, s2 = v0*v0+v1*v1+v2*v2;
  #pragma unroll
  for (int off=1; off<64; off<<=1){ s += __shfl_xor(s,off); s2 += __shfl_xor(s2,off); }
  float m = s*(1.f/192.f);
  float var = s2*(1.f/192.f) - m*m;
  float rstd = rsqrtf(var + eps);
  unsigned short* q = out + (size_t)row*CC;
  q[lane]     = bf16r_((v0-m)*rstd*g[lane]     + bta[lane]);
  q[lane+64]  = bf16r_((v1-m)*rstd*g[lane+64]  + bta[lane+64]);
  q[lane+128] = bf16r_((v2-m)*rstd*g[lane+128] + bta[lane+128]);
}

// ---------------- bf16 MFMA GEMM: out(MxN) = A(MxK) * W(NxK)^T ----------------
enum { EPI_NONE=0, EPI_RES=1, EPI_BIAS_GELU=2, EPI_BIAS_RES=3 };

template<int EPI, int OUTBF>
__global__ __launch_bounds__(256) void k_gemm_mfma(const unsigned short* __restrict__ A,
      const unsigned short* __restrict__ W, const float* __restrict__ bias,
      const float* __restrict__ res, void* __restrict__ outp, int M, int Nn, int Kk) {
  __shared__ unsigned short As[128][40];
  __shared__ unsigned short Bs[64][40];
  int tid = threadIdx.x;
  int m0 = blockIdx.y*128, n0 = blockIdx.x*64;
  int wid = tid>>6, lane = tid&63;
  int wm = wid*32;
  int fr = lane&15, fk = (lane>>4)*8;
  f32x4 acc[2][4];
  #pragma unroll
  for (int i=0;i<2;i++)
    #pragma unroll
    for (int j=0;j<4;j++) acc[i][j] = (f32x4){0.f,0.f,0.f,0.f};
  int arow = tid>>1, ak = (tid&1)*16;
  int wrow = tid>>2, wk = (tid&3)*8;
  const unsigned short* Ap = A + (size_t)(m0+arow)*Kk + ak;
  const unsigned short* Wp = W + (size_t)(n0+wrow)*Kk + wk;
  for (int k0=0; k0<Kk; k0+=32){
    __syncthreads();
    uint4 av0 = *(const uint4*)(Ap + k0);
    uint4 av1 = *(const uint4*)(Ap + k0 + 8);
    uint4 wv  = *(const uint4*)(Wp + k0);
    *(uint4*)&As[arow][ak]   = av0;
    *(uint4*)&As[arow][ak+8] = av1;
    *(uint4*)&Bs[wrow][wk]   = wv;
    __syncthreads();
    bf16x8 af[2], bfr[4];
    #pragma unroll
    for (int mi=0;mi<2;mi++) af[mi] = *(const bf16x8*)&As[wm + mi*16 + fr][fk];
    #pragma unroll
    for (int ni=0;ni<4;ni++) bfr[ni] = *(const bf16x8*)&Bs[ni*16 + fr][fk];
    #pragma unroll
    for (int mi=0;mi<2;mi++)
      #pragma unroll
      for (int ni=0;ni<4;ni++)
        acc[mi][ni] = __builtin_amdgcn_mfma_f32_16x16x32_bf16(af[mi], bfr[ni], acc[mi][ni], 0,0,0);
  }
  int rbase = (lane>>4)*4;
  #pragma unroll
  for (int mi=0;mi<2;mi++){
    #pragma unroll
    for (int ni=0;ni<4;ni++){
      int col = n0 + ni*16 + fr;
      float bv = (EPI==EPI_BIAS_GELU || EPI==EPI_BIAS_RES) ? bias[col] : 0.f;
      #pragma unroll
      for (int r=0;r<4;r++){
        int row = m0 + wm + mi*16 + rbase + r;
        float v = acc[mi][ni][r] + bv;
        if (EPI==EPI_BIAS_GELU) v = geluf_(v);
        if (EPI==EPI_RES || EPI==EPI_BIAS_RES) v += res[(size_t)row*Nn + col];
        if (OUTBF) ((unsigned short*)outp)[(size_t)row*Nn + col] = bf16r_(v);
        else       ((float*)outp)[(size_t)row*Nn + col] = v;
      }
    }
  }
}

// ---------------- depthwise conv 3x3 + bias + SiLU -> xc_l0 (B,L,Di) l-major ----------------
__global__ void k_conv_xx(const float* __restrict__ xz, const float* __restrict__ cw,
                          const float* __restrict__ cb, float* __restrict__ xc) {
  int idx = blockIdx.x*256 + threadIdx.x;
  if (idx >= BB*LL*DI) return;
  int d = idx % DI;
  int l = (idx / DI) % LL;
  int b = idx / (DI*LL);
  int h = l / WWW, w = l % WWW;
  float acc = cb[d];
  #pragma unroll
  for (int kh=0; kh<3; kh++){
    int hh = h + kh - 1; if (hh < 0 || hh >= HHH) continue;
    #pragma unroll
    for (int kw=0; kw<3; kw++){
      int ww2 = w + kw - 1; if (ww2 < 0 || ww2 >= WWW) continue;
      acc += xz[((size_t)(b*LL + hh*WWW + ww2))*(2*DI) + d] * cw[d*9 + kh*3 + kw];
    }
  }
  xc[idx] = siluf_(acc);
}

// ---------------- row permutation: (B, l=h*W+w, Di) -> (B, l1=w*H+h, Di) ----------------
__global__ void k_permrow(const float* __restrict__ in, float* __restrict__ out) {
  int idx = blockIdx.x*256 + threadIdx.x;
  if (idx >= BB*LL*DI) return;
  int d = idx % DI;
  int l = (idx / DI) % LL;
  int b = idx / (DI*LL);
  int h = l / WWW, w = l % WWW;
  out[((size_t)(b*LL + w*HHH + h))*DI + d] = in[idx];
}

// ---------------- (B,L,Di) -> (B,Di,L) transpose (for k_xdbl) ----------------
__global__ void k_trans_dl(const float* __restrict__ in, float* __restrict__ out) {
  __shared__ float t[32][33];
  int b = blockIdx.x, l0 = blockIdx.y*32, d0 = blockIdx.z*32;
  int tx = threadIdx.x, ty = threadIdx.y;
  #pragma unroll
  for (int r=0;r<4;r++){ int lr = ty + r*8;
    t[lr][tx] = in[((size_t)(b*LL + l0+lr))*DI + d0 + tx]; }
  __syncthreads();
  #pragma unroll
  for (int r=0;r<4;r++){ int dr = ty + r*8;
    out[((size_t)(b*DI + d0+dr))*LL + l0 + tx] = t[tx][dr]; }
}

// ---------------- (B,L,Di) -> (B,Di,L1) with l1 = w*H + h (for k_xdbl) ----------------
__global__ void k_trans_T(const float* __restrict__ in, float* __restrict__ out) {
  __shared__ float t[32][33];
  int bw = blockIdx.x;
  int b = bw / WWW, w = bw % WWW;
  int h0 = blockIdx.y*32, d0 = blockIdx.z*32;
  int tx = threadIdx.x, ty = threadIdx.y;
  #pragma unroll
  for (int r=0;r<4;r++){ int hr = ty + r*8; int h = h0 + hr;
    if (h < HHH) t[hr][tx] = in[((size_t)(b*LL + h*WWW + w))*DI + d0 + tx]; }
  __syncthreads();
  #pragma unroll
  for (int r=0;r<4;r++){ int dr = ty + r*8; int h = h0 + tx;
    if (h < HHH) out[((size_t)(b*DI + d0+dr))*LL + w*HHH + h] = t[tx][dr]; }
}

// -------- x_dbl records: xdblT[(bk*L + l)*48]: [0:12]=dts_raw, [16:32]=B, [32:48]=C --------
__global__ __launch_bounds__(256) void k_xdbl(const float* __restrict__ xc_dl, const float* __restrict__ xcT,
        const float* __restrict__ xpw, float* __restrict__ xdblT) {
  __shared__ float wsm[CP][32];
  int bk = blockIdx.x;
  int b = bk / KK, k = bk % KK;
  int l = blockIdx.y*64 + threadIdx.x;
  int cslot = threadIdx.y;
  const float* usrc = (k & 1) ? xcT : xc_dl;
  int lidx = (k < 2) ? l : (LL-1-l);
  float acc[11];
  #pragma unroll
  for (int j=0;j<11;j++) acc[j]=0.f;
  int tid = threadIdx.y*64 + threadIdx.x;
  for (int d0=0; d0<DI; d0+=32) {
    __syncthreads();
    for (int idx=tid; idx<CP*32; idx+=256) {
      int c = idx >> 5, dd = idx & 31;
      wsm[c][dd] = xpw[(k*CP + c)*DI + d0 + dd];
    }
    __syncthreads();
    #pragma unroll
    for (int dd=0; dd<32; dd++) {
      float u = usrc[((size_t)(b*DI + d0+dd))*LL + lidx];
      #pragma unroll
      for (int j=0;j<11;j++) acc[j] = fmaf(u, wsm[cslot*11+j][dd], acc[j]);
    }
  }
  size_t base = ((size_t)bk*LL + l)*48;
  #pragma unroll
  for (int j=0;j<11;j++){
    int c = cslot*11 + j;
    int off = (c < 12) ? c : (c + 4);
    xdblT[base + off] = acc[j];
  }
}

// ======== chunked selective scan, d-per-lane, l-major u ========
// grid (2, NCH, BB*KK), block 192: d = half*192 + tid
__global__ __launch_bounds__(192) void k_scan1(const float* __restrict__ xc_l0, const float* __restrict__ xc_l1,
        const float* __restrict__ xdblT, const float* __restrict__ dtw, const float* __restrict__ dtb,
        const float* __restrict__ alogs, float* __restrict__ hend, float* __restrict__ sumdt) {
  int half = blockIdx.x, ch = blockIdx.y, bk = blockIdx.z;
  int b = bk >> 2, k = bk & 3;
  int d = half*192 + threadIdx.x;
  int kd = k*DI + d;
  float w[12];
  #pragma unroll
  for (int r=0;r<12;r++) w[r] = dtw[kd*12 + r];
  float biasd = dtb[kd];
  float An2[16];
  #pragma unroll
  for (int n=0;n<16;n++) An2[n] = -__expf(alogs[kd*16 + n]) * 1.44269504f;
  const float* usrc = (k & 1) ? xc_l1 : xc_l0;
  bool rev = (k >= 2);
  const float* rec0 = xdblT + ((size_t)bk*LL + ch*CHL)*48;
  float h[16];
  #pragma unroll
  for (int n=0;n<16;n++) h[n]=0.f;
  float cum = 0.f;
  #pragma unroll 4
  for (int i=0;i<CHL;i++){
    int li = ch*CHL + i;
    int lsrc = rev ? (LL-1-li) : li;
    float uu = usrc[((size_t)(b*LL + lsrc))*DI + d];
    const float* rec = rec0 + (size_t)i*48;
    float a = biasd;
    #pragma unroll
    for (int r=0;r<12;r++) a = fmaf(rec[r], w[r], a);
    float dt = 0.69314718f * log2f(1.f + exp2f(a*1.44269504f));
    float dtu = dt*uu;
    cum += dt;
    #pragma unroll
    for (int n=0;n<16;n++){
      float dA = exp2f(dt*An2[n]);
      h[n] = fmaf(dA, h[n], dtu*rec[16+n]);
    }
  }
  size_t hb = ((size_t)(bk*NCH + ch)*DI + d)*16;
  #pragma unroll
  for (int n4=0;n4<4;n4++)
    *(float4*)&hend[hb + n4*4] = make_float4(h[n4*4],h[n4*4+1],h[n4*4+2],h[n4*4+3]);
  sumdt[(bk*NCH + ch)*DI + d] = cum;
}

// S2: per (b,k,4d-block) wave: prefix over chunks; hend[c] <- incoming state H_{c-1}
__global__ __launch_bounds__(64) void k_scanmid(const float* __restrict__ alogs,
        const float* __restrict__ sumdt, float* __restrict__ hend) {
  int bid = blockIdx.x;
  int dblk = bid % 96;
  int k = (bid/96) % KK;
  int b = bid/(96*KK);
  int lane = threadIdx.x;
  int d4 = lane>>4, n = lane&15;
  int d = dblk*4 + d4;
  int bk = b*KK + k;
  float Ac2 = -__expf(alogs[(k*DI+d)*16 + n]) * 1.44269504f;
  float H = 0.f;
  for (int c=0;c<NCH;c++){
    float sdt = sumdt[(bk*NCH + c)*DI + d];
    float aexp = exp2f(Ac2 * sdt);
    size_t idx = ((size_t)(bk*NCH + c)*DI + dblk*4)*16 + lane;
    float tmp = hend[idx];
    hend[idx] = H;
    H = fmaf(aexp, H, tmp);
  }
}

// S3: scan with incoming state, y out as bf16 rows (bk, L, Di)
__global__ __launch_bounds__(192) void k_scan2(const float* __restrict__ xc_l0, const float* __restrict__ xc_l1,
        const float* __restrict__ xdblT, const float* __restrict__ dtw, const float* __restrict__ dtb,
        const float* __restrict__ alogs, const float* __restrict__ Dsv,
        const float* __restrict__ hend, unsigned short* __restrict__ ysb) {
  int half = blockIdx.x, ch = blockIdx.y, bk = blockIdx.z;
  int b = bk >> 2, k = bk & 3;
  int d = half*192 + threadIdx.x;
  int kd = k*DI + d;
  float w[12];
  #pragma unroll
  for (int r=0;r<12;r++) w[r] = dtw[kd*12 + r];
  float biasd = dtb[kd];
  float Dd = Dsv[kd];
  float An2[16];
  #pragma unroll
  for (int n=0;n<16;n++) An2[n] = -__expf(alogs[kd*16 + n]) * 1.44269504f;
  const float* usrc = (k & 1) ? xc_l1 : xc_l0;
  bool rev = (k >= 2);
  const float* rec0 = xdblT + ((size_t)bk*LL + ch*CHL)*48;
  float h[16];
  size_t hb = ((size_t)(bk*NCH + ch)*DI + d)*16;
  #pragma unroll
  for (int n4=0;n4<4;n4++){
    float4 hv = *(const float4*)&hend[hb + n4*4];
    h[n4*4]=hv.x; h[n4*4+1]=hv.y; h[n4*4+2]=hv.z; h[n4*4+3]=hv.w;
  }
  #pragma unroll 4
  for (int i=0;i<CHL;i++){
    int li = ch*CHL + i;
    int lsrc = rev ? (LL-1-li) : li;
    float uu = usrc[((size_t)(b*LL + lsrc))*DI + d];
    const float* rec = rec0 + (size_t)i*48;
    float a = biasd;
    #pragma unroll
    for (int r=0;r<12;r++) a = fmaf(rec[r], w[r], a);
    float dt = 0.69314718f * log2f(1.f + exp2f(a*1.44269504f));
    float dtu = dt*uu;
    float y = uu*Dd;
    #pragma unroll
    for (int n=0;n<16;n++){
      float dA = exp2f(dt*An2[n]);
      h[n] = fmaf(dA, h[n], dtu*rec[16+n]);
      y = fmaf(h[n], rec[32+n], y);
    }
    ysb[((size_t)(bk*LL + li))*DI + d] = bf16r_(y);
  }
}

// ---------------- fused combine + LN(Di) + silu(z) gate -> a2 (B,L,Di) bf16 ----------------
__global__ __launch_bounds__(384) void k_fuse(const unsigned short* __restrict__ ysb,
      const float* __restrict__ xz, const float* __restrict__ og, const float* __restrict__ ob,
      unsigned short* __restrict__ a2) {
  __shared__ float sa[6], sb[6];
  int b = blockIdx.x / LL, l = blockIdx.x % LL;
  int d = threadIdx.x;
  int h_ = l / WWW, w_ = l % WWW;
  int l1 = w_*HHH + h_;
  float y = bf2f_(ysb[((size_t)((b*KK+0)*LL + l))*DI + d])
          + bf2f_(ysb[((size_t)((b*KK+1)*LL + l1))*DI + d])
          + bf2f_(ysb[((size_t)((b*KK+2)*LL + (LL-1-l)))*DI + d])
          + bf2f_(ysb[((size_t)((b*KK+3)*LL + (LL-1-l1)))*DI + d]);
  float s = y, s2 = y*y;
  #pragma unroll
  for (int off=1; off<64; off<<=1){ s += __shfl_xor(s,off); s2 += __shfl_xor(s2,off); }
  int wid = d >> 6;
  if ((d & 63) == 0){ sa[wid] = s; sb[wid] = s2; }
  __syncthreads();
  s = sa[0]+sa[1]+sa[2]+sa[3]+sa[4]+sa[5];
  s2 = sb[0]+sb[1]+sb[2]+sb[3]+sb[4]+sb[5];
  float m = s*(1.f/DI);
  float var = s2*(1.f/DI) - m*m;
  float rstd = rsqrtf(var + 1e-5f);
  float v = (y - m)*rstd*og[d] + ob[d];
  float z = xz[((size_t)(b*LL + l))*(2*DI) + DI + d];
  a2[((size_t)(b*LL + l))*DI + d] = bf16r_(v * siluf_(z));
}

extern "C" void kernel_launch(void* const* d_in, const int* in_sizes, int n_in,
                              void* d_out, int out_size, void* d_ws, size_t ws_size,
                              hipStream_t stream) {
  (void)in_sizes; (void)n_in; (void)out_size; (void)ws_size;
  const float* x       = (const float*)d_in[0];
  const float* cpe1_w  = (const float*)d_in[1];
  const float* cpe1_b  = (const float*)d_in[2];
  const float* ln1_g   = (const float*)d_in[3];
  const float* ln1_b   = (const float*)d_in[4];
  const float* in_proj = (const float*)d_in[5];
  const float* conv_w  = (const float*)d_in[6];
  const float* conv_b  = (const float*)d_in[7];
  const float* x_proj  = (const float*)d_in[8];
  const float* dt_w    = (const float*)d_in[9];
  const float* dt_b    = (const float*)d_in[10];
  const float* A_logs  = (const float*)d_in[11];
  const float* Dsv     = (const float*)d_in[12];
  const float* onorm_g = (const float*)d_in[13];
  const float* onorm_b = (const float*)d_in[14];
  const float* out_proj= (const float*)d_in[15];
  const float* cpe2_w  = (const float*)d_in[16];
  const float* cpe2_b  = (const float*)d_in[17];
  const float* ln2_g   = (const float*)d_in[18];
  const float* ln2_b   = (const float*)d_in[19];
  const float* fc1_w   = (const float*)d_in[20];
  const float* fc1_b   = (const float*)d_in[21];
  const float* fc2_w   = (const float*)d_in[22];
  const float* fc2_b   = (const float*)d_in[23];
  float* out = (float*)d_out;
  float* wsf = (float*)d_ws;

  float* x1    = wsf;                        // 1,204,224 f
  float* xlnf  = x1 + 1204224;               // 1,204,224 f
  float* xz    = xlnf + 1204224;             // 4,816,896 f
  float* xc_l0 = xz + 4816896;               // 2,408,448 f  (B,L,Di)
  float* xc_dl = xc_l0 + 2408448;            // 2,408,448 f  (B,Di,L)  [xdbl only]
  float* xcT   = xc_dl + 2408448;            // 2,408,448 f  (B,Di,L1) [xdbl], then xc_l1
  float* ysbf  = xcT + 2408448;              // 4,816,896 f = 9,633,792 bf16 (bk,L,Di)
  float* hend  = ysbf + 4816896;             // 4,816,896 f  (bk,NCH,Di,16)
  float* sumdt = hend + 4816896;             // 301,056 f
  float* xdblT = sumdt + 301056;             // 1,204,224 f
  unsigned short* wbf = (unsigned short*)(xdblT + 1204224); // 516,096 bf16 = 258,048 f
  // total = 25,847,808 f = 103.4 MB
  // aliases (lifetime-disjoint)
  unsigned short* xln  = (unsigned short*)xlnf;
  unsigned short* xln2 = (unsigned short*)xlnf;
  float* xc_l1 = xcT;                            // after k_xdbl
  unsigned short* ysb = (unsigned short*)ysbf;
  unsigned short* a2 = (unsigned short*)xdblT;   // after scan2 (2,408,448 bf16 fits)
  float* x2   = xc_l0;                           // after k_fuse
  float* x3   = xz;                              // after k_fuse
  unsigned short* hbuf = (unsigned short*)ysbf;  // after k_fuse
  unsigned short* wIn  = wbf;
  unsigned short* wOut = wbf + 147456;
  unsigned short* wF1  = wbf + 221184;
  unsigned short* wF2  = wbf + 368640;

  k_cvtw<<<2016, 256, 0, stream>>>(in_proj, out_proj, fc1_w, fc2_w, wbf);
  k_dwconv_res<<<(BB*HHH*WWW*CC+255)/256, 256, 0, stream>>>(x, cpe1_w, cpe1_b, x1);
  k_ln192<<<BL/4, 256, 0, stream>>>(x1, ln1_g, ln1_b, xln, 1e-6f);
  k_gemm_mfma<EPI_NONE,0><<<dim3(768/64, BL/128), 256, 0, stream>>>(xln, wIn, nullptr, nullptr, xz, BL, 2*DI, CC);
  k_conv_xx<<<(BB*LL*DI+255)/256, 256, 0, stream>>>(xz, conv_w, conv_b, xc_l0);
  k_trans_dl<<<dim3(BB, 98, 12), dim3(32,8), 0, stream>>>(xc_l0, xc_dl);
  k_trans_T<<<dim3(BB*WWW, 2, 12), dim3(32,8), 0, stream>>>(xc_l0, xcT);
  k_xdbl<<<dim3(BB*KK, 49), dim3(64,4), 0, stream>>>(xc_dl, xcT, x_proj, xdblT);
  k_permrow<<<(BB*LL*DI+255)/256, 256, 0, stream>>>(xc_l0, xc_l1);
  k_scan1<<<dim3(2, NCH, BB*KK), 192, 0, stream>>>(xc_l0, xc_l1, xdblT, dt_w, dt_b, A_logs, hend, sumdt);
  k_scanmid<<<BB*KK*96, 64, 0, stream>>>(A_logs, sumdt, hend);
  k_scan2<<<dim3(2, NCH, BB*KK), 192, 0, stream>>>(xc_l0, xc_l1, xdblT, dt_w, dt_b, A_logs, Dsv, hend, ysb);
  k_fuse<<<BB*LL, 384, 0, stream>>>(ysb, xz, onorm_g, onorm_b, a2);
  k_gemm_mfma<EPI_RES,0><<<dim3(192/64, BL/128), 256, 0, stream>>>(a2, wOut, nullptr, x1, x2, BL, CC, DI);
  k_dwconv_res<<<(BB*HHH*WWW*CC+255)/256, 256, 0, stream>>>(x2, cpe2_w, cpe2_b, x3);
  k_ln192<<<BL/4, 256, 0, stream>>>(x3, ln2_g, ln2_b, xln2, 1e-6f);
  k_gemm_mfma<EPI_BIAS_GELU,1><<<dim3(768/64, BL/128), 256, 0, stream>>>(xln2, wF1, fc1_b, nullptr, hbuf, BL, HIDN, CC);
  k_gemm_mfma<EPI_BIAS_RES,0><<<dim3(192/64, BL/128), 256, 0, stream>>>(hbuf, wF2, fc2_b, x3, out, BL, CC, HIDN);
}

// Round 5
// 284.536 us; speedup vs baseline: 3.0831x; 1.2533x over previous
//
#include <hip/hip_runtime.h>
#include <math.h>

#define BB 2
#define HHH 56
#define WWW 56
#define CC 192
#define LL 3136
#define DI 384
#define KK 4
#define NN 16
#define RR 12
#define CP 44
#define HIDN 768
#define BL (BB*LL)
#define NCH 98   // chunks per sequence
#define CHL 32   // chunk length (98*32 = 3136)

typedef __attribute__((ext_vector_type(8))) short bf16x8;
typedef __attribute__((ext_vector_type(4))) float f32x4;

__device__ __forceinline__ float siluf_(float x){ return x/(1.f+__expf(-x)); }
__device__ __forceinline__ float geluf_(float x){ return 0.5f*x*(1.f+erff(x*0.70710678118654752f)); }
__device__ __forceinline__ unsigned short bf16r_(float x){
  unsigned int u = __float_as_uint(x);
  u += 0x7FFFu + ((u>>16)&1u);
  return (unsigned short)(u>>16);
}
__device__ __forceinline__ float bf2f_(unsigned short u){
  return __uint_as_float(((unsigned int)u)<<16);
}

// ---------------- weight fp32 -> bf16 convert (4 segments) ----------------
__global__ void k_cvtw(const float* __restrict__ s0, const float* __restrict__ s1,
                       const float* __restrict__ s2, const float* __restrict__ s3,
                       unsigned short* __restrict__ dst){
  int i = blockIdx.x*256 + threadIdx.x;
  if      (i < 147456) dst[i] = bf16r_(s0[i]);
  else if (i < 221184) dst[i] = bf16r_(s1[i-147456]);
  else if (i < 368640) dst[i] = bf16r_(s2[i-221184]);
  else if (i < 516096) dst[i] = bf16r_(s3[i-368640]);
}

// ---------------- depthwise 3x3 + residual (NHWC, C=192) ----------------
__global__ void k_dwconv_res(const float* __restrict__ in, const float* __restrict__ wgt,
                             const float* __restrict__ bias, float* __restrict__ out) {
  int idx = blockIdx.x*256 + threadIdx.x;
  const int total = BB*HHH*WWW*CC;
  if (idx >= total) return;
  int c = idx % CC;
  int w = (idx / CC) % WWW;
  int h = (idx / (CC*WWW)) % HHH;
  int b = idx / (CC*WWW*HHH);
  float acc = bias[c];
  #pragma unroll
  for (int kh=0; kh<3; kh++){
    int hh = h + kh - 1; if (hh < 0 || hh >= HHH) continue;
    #pragma unroll
    for (int kw=0; kw<3; kw++){
      int ww = w + kw - 1; if (ww < 0 || ww >= WWW) continue;
      acc += in[((b*HHH+hh)*WWW+ww)*CC + c] * wgt[c*9 + kh*3 + kw];
    }
  }
  out[idx] = in[idx] + acc;
}

// ---------------- LayerNorm over D=192, one wave per row, bf16 out ----------------
__global__ void k_ln192(const float* __restrict__ in, const float* __restrict__ g,
                        const float* __restrict__ bta, unsigned short* __restrict__ out, float eps) {
  int row = blockIdx.x*4 + (threadIdx.x>>6);
  int lane = threadIdx.x & 63;
  const float* p = in + (size_t)row*CC;
  float v0=p[lane], v1=p[lane+64], v2=p[lane+128];
  float s = v0+v1+v2, s2 = v0*v0+v1*v1+v2*v2;
  #pragma unroll
  for (int off=1; off<64; off<<=1){ s += __shfl_xor(s,off); s2 += __shfl_xor(s2,off); }
  float m = s*(1.f/192.f);
  float var = s2*(1.f/192.f) - m*m;
  float rstd = rsqrtf(var + eps);
  unsigned short* q = out + (size_t)row*CC;
  q[lane]     = bf16r_((v0-m)*rstd*g[lane]     + bta[lane]);
  q[lane+64]  = bf16r_((v1-m)*rstd*g[lane+64]  + bta[lane+64]);
  q[lane+128] = bf16r_((v2-m)*rstd*g[lane+128] + bta[lane+128]);
}

// ---------------- bf16 MFMA GEMM: out(MxN) = A(MxK) * W(NxK)^T ----------------
enum { EPI_NONE=0, EPI_RES=1, EPI_BIAS_GELU=2, EPI_BIAS_RES=3 };

template<int EPI, int OUTBF>
__global__ __launch_bounds__(256) void k_gemm_mfma(const unsigned short* __restrict__ A,
      const unsigned short* __restrict__ W, const float* __restrict__ bias,
      const float* __restrict__ res, void* __restrict__ outp, int M, int Nn, int Kk) {
  __shared__ unsigned short As[128][40];
  __shared__ unsigned short Bs[64][40];
  int tid = threadIdx.x;
  int m0 = blockIdx.y*128, n0 = blockIdx.x*64;
  int wid = tid>>6, lane = tid&63;
  int wm = wid*32;
  int fr = lane&15, fk = (lane>>4)*8;
  f32x4 acc[2][4];
  #pragma unroll
  for (int i=0;i<2;i++)
    #pragma unroll
    for (int j=0;j<4;j++) acc[i][j] = (f32x4){0.f,0.f,0.f,0.f};
  int arow = tid>>1, ak = (tid&1)*16;
  int wrow = tid>>2, wk = (tid&3)*8;
  const unsigned short* Ap = A + (size_t)(m0+arow)*Kk + ak;
  const unsigned short* Wp = W + (size_t)(n0+wrow)*Kk + wk;
  for (int k0=0; k0<Kk; k0+=32){
    __syncthreads();
    uint4 av0 = *(const uint4*)(Ap + k0);
    uint4 av1 = *(const uint4*)(Ap + k0 + 8);
    uint4 wv  = *(const uint4*)(Wp + k0);
    *(uint4*)&As[arow][ak]   = av0;
    *(uint4*)&As[arow][ak+8] = av1;
    *(uint4*)&Bs[wrow][wk]   = wv;
    __syncthreads();
    bf16x8 af[2], bfr[4];
    #pragma unroll
    for (int mi=0;mi<2;mi++) af[mi] = *(const bf16x8*)&As[wm + mi*16 + fr][fk];
    #pragma unroll
    for (int ni=0;ni<4;ni++) bfr[ni] = *(const bf16x8*)&Bs[ni*16 + fr][fk];
    #pragma unroll
    for (int mi=0;mi<2;mi++)
      #pragma unroll
      for (int ni=0;ni<4;ni++)
        acc[mi][ni] = __builtin_amdgcn_mfma_f32_16x16x32_bf16(af[mi], bfr[ni], acc[mi][ni], 0,0,0);
  }
  int rbase = (lane>>4)*4;
  #pragma unroll
  for (int mi=0;mi<2;mi++){
    #pragma unroll
    for (int ni=0;ni<4;ni++){
      int col = n0 + ni*16 + fr;
      float bv = (EPI==EPI_BIAS_GELU || EPI==EPI_BIAS_RES) ? bias[col] : 0.f;
      #pragma unroll
      for (int r=0;r<4;r++){
        int row = m0 + wm + mi*16 + rbase + r;
        float v = acc[mi][ni][r] + bv;
        if (EPI==EPI_BIAS_GELU) v = geluf_(v);
        if (EPI==EPI_RES || EPI==EPI_BIAS_RES) v += res[(size_t)row*Nn + col];
        if (OUTBF) ((unsigned short*)outp)[(size_t)row*Nn + col] = bf16r_(v);
        else       ((float*)outp)[(size_t)row*Nn + col] = v;
      }
    }
  }
}

// ---------- depthwise conv 3x3 + bias + SiLU -> xc_l0 (B,L,Di) AND xc_l1 (B,L1,Di) ----------
__global__ void k_conv_xx(const float* __restrict__ xz, const float* __restrict__ cw,
                          const float* __restrict__ cb, float* __restrict__ xc0,
                          float* __restrict__ xc1) {
  int idx = blockIdx.x*256 + threadIdx.x;
  if (idx >= BB*LL*DI) return;
  int d = idx % DI;
  int l = (idx / DI) % LL;
  int b = idx / (DI*LL);
  int h = l / WWW, w = l % WWW;
  float acc = cb[d];
  #pragma unroll
  for (int kh=0; kh<3; kh++){
    int hh = h + kh - 1; if (hh < 0 || hh >= HHH) continue;
    #pragma unroll
    for (int kw=0; kw<3; kw++){
      int ww2 = w + kw - 1; if (ww2 < 0 || ww2 >= WWW) continue;
      acc += xz[((size_t)(b*LL + hh*WWW + ww2))*(2*DI) + d] * cw[d*9 + kh*3 + kw];
    }
  }
  float v = siluf_(acc);
  xc0[idx] = v;
  xc1[((size_t)(b*LL + w*HHH + h))*DI + d] = v;
}

// -------- x_dbl records from l-major u, LDS-staged tile --------
// xdblT[(bk*L + l)*48]: [0:12]=dts_raw, [16:32]=B, [32:48]=C
__global__ __launch_bounds__(256) void k_xdbl(const float* __restrict__ xc_l0, const float* __restrict__ xc_l1,
        const float* __restrict__ xpw, float* __restrict__ xdblT) {
  __shared__ float wsm[CP][32];
  __shared__ float usm[64][33];
  int bk = blockIdx.x;
  int b = bk >> 2, k = bk & 3;
  int l0 = blockIdx.y*64;
  int tid = threadIdx.x;
  int ll = tid & 63, cslot = tid >> 6;
  const float* usrc = (k & 1) ? xc_l1 : xc_l0;
  bool rev = (k >= 2);
  float acc[11];
  #pragma unroll
  for (int j=0;j<11;j++) acc[j]=0.f;
  int sr = tid >> 5, sd = tid & 31;
  for (int d0=0; d0<DI; d0+=32) {
    __syncthreads();
    for (int i2=tid; i2<CP*32; i2+=256) {
      int c = i2 >> 5, dd = i2 & 31;
      wsm[c][dd] = xpw[(k*CP + c)*DI + d0 + dd];
    }
    #pragma unroll
    for (int rr=0; rr<8; rr++){
      int row = sr + rr*8;
      int l = l0 + row;
      int lsrc = rev ? (LL-1-l) : l;
      usm[row][sd] = usrc[((size_t)(b*LL + lsrc))*DI + d0 + sd];
    }
    __syncthreads();
    #pragma unroll
    for (int dd=0; dd<32; dd++) {
      float u = usm[ll][dd];
      #pragma unroll
      for (int j=0;j<11;j++) acc[j] = fmaf(u, wsm[cslot*11+j][dd], acc[j]);
    }
  }
  size_t base = ((size_t)bk*LL + l0 + ll)*48;
  #pragma unroll
  for (int j=0;j<11;j++){
    int c = cslot*11 + j;
    int off = (c < 12) ? c : (c + 4);
    xdblT[base + off] = acc[j];
  }
}

// ======== chunked selective scan, d-per-lane, single-wave blocks ========
// grid (6, NCH, BB*KK), block 64: d = blockIdx.x*64 + lane
template<int PASS>
__global__ __launch_bounds__(64) void k_scan(const float* __restrict__ xc_l0, const float* __restrict__ xc_l1,
        const float* __restrict__ xdblT, const float* __restrict__ dtw, const float* __restrict__ dtb,
        const float* __restrict__ alogs, const float* __restrict__ Dsv,
        float* __restrict__ hend, float* __restrict__ sumdt, unsigned short* __restrict__ ysb) {
  int ch = blockIdx.y, bk = blockIdx.z;
  int b = bk >> 2, k = bk & 3;
  int d = blockIdx.x*64 + threadIdx.x;
  int kd = k*DI + d;
  float w[12];
  #pragma unroll
  for (int r=0;r<12;r++) w[r] = dtw[kd*12 + r];
  float biasd = dtb[kd];
  float Dd = (PASS==1) ? Dsv[kd] : 0.f;
  float An2[16];
  #pragma unroll
  for (int n=0;n<16;n++) An2[n] = -__expf(alogs[kd*16 + n]) * 1.44269504f;
  bool pw = true;
  #pragma unroll
  for (int n=1;n<16;n++) pw = pw && (fabsf(An2[n] - (float)(n+1)*An2[0]) <= 1e-3f*(float)(n+1)*fabsf(An2[0]));
  const float* usrc = (k & 1) ? xc_l1 : xc_l0;
  bool rev = (k >= 2);
  const float* rec0 = xdblT + ((size_t)bk*LL + ch*CHL)*48;
  float h[16];
  size_t hb = ((size_t)(bk*NCH + ch)*DI + d)*16;
  if (PASS==0){
    #pragma unroll
    for (int n=0;n<16;n++) h[n]=0.f;
  } else {
    #pragma unroll
    for (int n4=0;n4<4;n4++){
      float4 hv = *(const float4*)&hend[hb + n4*4];
      h[n4*4]=hv.x; h[n4*4+1]=hv.y; h[n4*4+2]=hv.z; h[n4*4+3]=hv.w;
    }
  }
  float cum = 0.f;
  #pragma unroll 2
  for (int i=0;i<CHL;i++){
    int li = ch*CHL + i;
    int lsrc = rev ? (LL-1-li) : li;
    float uu = usrc[((size_t)(b*LL + lsrc))*DI + d];
    const float* rec = rec0 + (size_t)i*48;
    float4 t0 = *(const float4*)(rec);
    float4 t1 = *(const float4*)(rec+4);
    float4 t2 = *(const float4*)(rec+8);
    float4 B0 = *(const float4*)(rec+16);
    float4 B1 = *(const float4*)(rec+20);
    float4 B2 = *(const float4*)(rec+24);
    float4 B3 = *(const float4*)(rec+28);
    float a0 = fmaf(t0.x,w[0], fmaf(t0.y,w[1], fmaf(t0.z,w[2], t0.w*w[3])));
    float a1 = fmaf(t1.x,w[4], fmaf(t1.y,w[5], fmaf(t1.z,w[6], t1.w*w[7])));
    float a2 = fmaf(t2.x,w[8], fmaf(t2.y,w[9], fmaf(t2.z,w[10], t2.w*w[11])));
    float a = biasd + a0 + (a1 + a2);
    float dt = 0.69314718f * log2f(1.f + exp2f(a*1.44269504f));
    float dtu = dt*uu;
    if (PASS==0) cum += dt;
    float dA[16];
    if (pw){
      float r = exp2f(dt*An2[0]);
      float p = r; dA[0] = p;
      #pragma unroll
      for (int n=1;n<16;n++){ p *= r; dA[n] = p; }
    } else {
      #pragma unroll
      for (int n=0;n<16;n++) dA[n] = exp2f(dt*An2[n]);
    }
    float Bv[16] = {B0.x,B0.y,B0.z,B0.w, B1.x,B1.y,B1.z,B1.w,
                    B2.x,B2.y,B2.z,B2.w, B3.x,B3.y,B3.z,B3.w};
    #pragma unroll
    for (int n=0;n<16;n++) h[n] = fmaf(dA[n], h[n], dtu*Bv[n]);
    if (PASS==1){
      float4 C0 = *(const float4*)(rec+32);
      float4 C1 = *(const float4*)(rec+36);
      float4 C2 = *(const float4*)(rec+40);
      float4 C3 = *(const float4*)(rec+44);
      float y0 = fmaf(h[0], C0.x, fmaf(h[1], C0.y, fmaf(h[2], C0.z, h[3]*C0.w)));
      float y1 = fmaf(h[4], C1.x, fmaf(h[5], C1.y, fmaf(h[6], C1.z, h[7]*C1.w)));
      float y2 = fmaf(h[8], C2.x, fmaf(h[9], C2.y, fmaf(h[10],C2.z, h[11]*C2.w)));
      float y3 = fmaf(h[12],C3.x, fmaf(h[13],C3.y, fmaf(h[14],C3.z, h[15]*C3.w)));
      float y = fmaf(uu, Dd, (y0+y1)+(y2+y3));
      ysb[((size_t)(bk*LL + li))*DI + d] = bf16r_(y);
    }
  }
  if (PASS==0){
    #pragma unroll
    for (int n4=0;n4<4;n4++)
      *(float4*)&hend[hb + n4*4] = make_float4(h[n4*4],h[n4*4+1],h[n4*4+2],h[n4*4+3]);
    sumdt[(bk*NCH + ch)*DI + d] = cum;
  }
}

// S2: per (b,k,4d-block) wave: prefix over chunks; hend[c] <- incoming state H_{c-1}
__global__ __launch_bounds__(64) void k_scanmid(const float* __restrict__ alogs,
        const float* __restrict__ sumdt, float* __restrict__ hend) {
  int bid = blockIdx.x;
  int dblk = bid % 96;
  int k = (bid/96) % KK;
  int b = bid/(96*KK);
  int lane = threadIdx.x;
  int d4 = lane>>4, n = lane&15;
  int d = dblk*4 + d4;
  int bk = b*KK + k;
  float Ac2 = -__expf(alogs[(k*DI+d)*16 + n]) * 1.44269504f;
  float H = 0.f;
  for (int c=0;c<NCH;c++){
    float sdt = sumdt[(bk*NCH + c)*DI + d];
    float aexp = exp2f(Ac2 * sdt);
    size_t idx = ((size_t)(bk*NCH + c)*DI + dblk*4)*16 + lane;
    float tmp = hend[idx];
    hend[idx] = H;
    H = fmaf(aexp, H, tmp);
  }
}

// ---------------- fused combine + LN(Di) + silu(z) gate -> a2 (B,L,Di) bf16 ----------------
__global__ __launch_bounds__(384) void k_fuse(const unsigned short* __restrict__ ysb,
      const float* __restrict__ xz, const float* __restrict__ og, const float* __restrict__ ob,
      unsigned short* __restrict__ a2) {
  __shared__ float sa[6], sb[6];
  int b = blockIdx.x / LL, l = blockIdx.x % LL;
  int d = threadIdx.x;
  int h_ = l / WWW, w_ = l % WWW;
  int l1 = w_*HHH + h_;
  float y = bf2f_(ysb[((size_t)((b*KK+0)*LL + l))*DI + d])
          + bf2f_(ysb[((size_t)((b*KK+1)*LL + l1))*DI + d])
          + bf2f_(ysb[((size_t)((b*KK+2)*LL + (LL-1-l)))*DI + d])
          + bf2f_(ysb[((size_t)((b*KK+3)*LL + (LL-1-l1)))*DI + d]);
  float s = y, s2 = y*y;
  #pragma unroll
  for (int off=1; off<64; off<<=1){ s += __shfl_xor(s,off); s2 += __shfl_xor(s2,off); }
  int wid = d >> 6;
  if ((d & 63) == 0){ sa[wid] = s; sb[wid] = s2; }
  __syncthreads();
  s = sa[0]+sa[1]+sa[2]+sa[3]+sa[4]+sa[5];
  s2 = sb[0]+sb[1]+sb[2]+sb[3]+sb[4]+sb[5];
  float m = s*(1.f/DI);
  float var = s2*(1.f/DI) - m*m;
  float rstd = rsqrtf(var + 1e-5f);
  float v = (y - m)*rstd*og[d] + ob[d];
  float z = xz[((size_t)(b*LL + l))*(2*DI) + DI + d];
  a2[((size_t)(b*LL + l))*DI + d] = bf16r_(v * siluf_(z));
}

extern "C" void kernel_launch(void* const* d_in, const int* in_sizes, int n_in,
                              void* d_out, int out_size, void* d_ws, size_t ws_size,
                              hipStream_t stream) {
  (void)in_sizes; (void)n_in; (void)out_size; (void)ws_size;
  const float* x       = (const float*)d_in[0];
  const float* cpe1_w  = (const float*)d_in[1];
  const float* cpe1_b  = (const float*)d_in[2];
  const float* ln1_g   = (const float*)d_in[3];
  const float* ln1_b   = (const float*)d_in[4];
  const float* in_proj = (const float*)d_in[5];
  const float* conv_w  = (const float*)d_in[6];
  const float* conv_b  = (const float*)d_in[7];
  const float* x_proj  = (const float*)d_in[8];
  const float* dt_w    = (const float*)d_in[9];
  const float* dt_b    = (const float*)d_in[10];
  const float* A_logs  = (const float*)d_in[11];
  const float* Dsv     = (const float*)d_in[12];
  const float* onorm_g = (const float*)d_in[13];
  const float* onorm_b = (const float*)d_in[14];
  const float* out_proj= (const float*)d_in[15];
  const float* cpe2_w  = (const float*)d_in[16];
  const float* cpe2_b  = (const float*)d_in[17];
  const float* ln2_g   = (const float*)d_in[18];
  const float* ln2_b   = (const float*)d_in[19];
  const float* fc1_w   = (const float*)d_in[20];
  const float* fc1_b   = (const float*)d_in[21];
  const float* fc2_w   = (const float*)d_in[22];
  const float* fc2_b   = (const float*)d_in[23];
  float* out = (float*)d_out;
  float* wsf = (float*)d_ws;

  float* x1    = wsf;                        // 1,204,224 f
  float* xlnf  = x1 + 1204224;               // 1,204,224 f
  float* xz    = xlnf + 1204224;             // 4,816,896 f
  float* xc_l0 = xz + 4816896;               // 2,408,448 f  (B,L,Di)
  float* xc_l1 = xc_l0 + 2408448;            // 2,408,448 f  (B,L1,Di)
  float* ysbf  = xc_l1 + 2408448;            // 4,816,896 f = 9,633,792 bf16 (bk,L,Di)
  float* hend  = ysbf + 4816896;             // 4,816,896 f  (bk,NCH,Di,16)
  float* sumdt = hend + 4816896;             // 301,056 f
  float* xdblT = sumdt + 301056;             // 1,204,224 f
  unsigned short* wbf = (unsigned short*)(xdblT + 1204224); // 516,096 bf16 = 258,048 f
  // total = 23,439,360 f ~ 93.8 MB
  // aliases (lifetime-disjoint)
  unsigned short* xln  = (unsigned short*)xlnf;
  unsigned short* xln2 = (unsigned short*)xlnf;
  unsigned short* ysb = (unsigned short*)ysbf;
  unsigned short* a2 = (unsigned short*)xdblT;   // after scan2 (2,408,448 bf16 fits)
  float* x2   = xc_l0;                           // after k_fuse
  float* x3   = xz;                              // after k_fuse
  unsigned short* hbuf = (unsigned short*)ysbf;  // after k_fuse
  unsigned short* wIn  = wbf;
  unsigned short* wOut = wbf + 147456;
  unsigned short* wF1  = wbf + 221184;
  unsigned short* wF2  = wbf + 368640;

  k_cvtw<<<2016, 256, 0, stream>>>(in_proj, out_proj, fc1_w, fc2_w, wbf);
  k_dwconv_res<<<(BB*HHH*WWW*CC+255)/256, 256, 0, stream>>>(x, cpe1_w, cpe1_b, x1);
  k_ln192<<<BL/4, 256, 0, stream>>>(x1, ln1_g, ln1_b, xln, 1e-6f);
  k_gemm_mfma<EPI_NONE,0><<<dim3(768/64, BL/128), 256, 0, stream>>>(xln, wIn, nullptr, nullptr, xz, BL, 2*DI, CC);
  k_conv_xx<<<(BB*LL*DI+255)/256, 256, 0, stream>>>(xz, conv_w, conv_b, xc_l0, xc_l1);
  k_xdbl<<<dim3(BB*KK, 49), 256, 0, stream>>>(xc_l0, xc_l1, x_proj, xdblT);
  k_scan<0><<<dim3(6, NCH, BB*KK), 64, 0, stream>>>(xc_l0, xc_l1, xdblT, dt_w, dt_b, A_logs, Dsv, hend, sumdt, ysb);
  k_scanmid<<<BB*KK*96, 64, 0, stream>>>(A_logs, sumdt, hend);
  k_scan<1><<<dim3(6, NCH, BB*KK), 64, 0, stream>>>(xc_l0, xc_l1, xdblT, dt_w, dt_b, A_logs, Dsv, hend, sumdt, ysb);
  k_fuse<<<BB*LL, 384, 0, stream>>>(ysb, xz, onorm_g, onorm_b, a2);
  k_gemm_mfma<EPI_RES,0><<<dim3(192/64, BL/128), 256, 0, stream>>>(a2, wOut, nullptr, x1, x2, BL, CC, DI);
  k_dwconv_res<<<(BB*HHH*WWW*CC+255)/256, 256, 0, stream>>>(x2, cpe2_w, cpe2_b, x3);
  k_ln192<<<BL/4, 256, 0, stream>>>(x3, ln2_g, ln2_b, xln2, 1e-6f);
  k_gemm_mfma<EPI_BIAS_GELU,1><<<dim3(768/64, BL/128), 256, 0, stream>>>(xln2, wF1, fc1_b, nullptr, hbuf, BL, HIDN, CC);
  k_gemm_mfma<EPI_BIAS_RES,0><<<dim3(192/64, BL/128), 256, 0, stream>>>(hbuf, wF2, fc2_b, x3, out, BL, CC, HIDN);
}

// Round 7
// 246.572 us; speedup vs baseline: 3.5578x; 1.1540x over previous
//
#include <hip/hip_runtime.h>
#include <math.h>

#define BB 2
#define HHH 56
#define WWW 56
#define CC 192
#define LL 3136
#define DI 384
#define KK 4
#define NN 16
#define RR 12
#define CP 44
#define HIDN 768
#define BL (BB*LL)
#define NCH 98   // chunks per sequence
#define CHL 32   // chunk length (98*32 = 3136)

typedef __attribute__((ext_vector_type(8))) short bf16x8;
typedef __attribute__((ext_vector_type(4))) float f32x4;

__device__ __forceinline__ float siluf_(float x){ return x/(1.f+__expf(-x)); }
__device__ __forceinline__ float geluf_(float x){ return 0.5f*x*(1.f+erff(x*0.70710678118654752f)); }
__device__ __forceinline__ unsigned short bf16r_(float x){
  unsigned int u = __float_as_uint(x);
  u += 0x7FFFu + ((u>>16)&1u);
  return (unsigned short)(u>>16);
}
__device__ __forceinline__ float bf2f_(unsigned short u){
  return __uint_as_float(((unsigned int)u)<<16);
}

// ---------------- weight fp32 -> bf16 convert (4 segments) ----------------
__global__ void k_cvtw(const float* __restrict__ s0, const float* __restrict__ s1,
                       const float* __restrict__ s2, const float* __restrict__ s3,
                       unsigned short* __restrict__ dst){
  int i = blockIdx.x*256 + threadIdx.x;
  if      (i < 147456) dst[i] = bf16r_(s0[i]);
  else if (i < 221184) dst[i] = bf16r_(s1[i-147456]);
  else if (i < 368640) dst[i] = bf16r_(s2[i-221184]);
  else if (i < 516096) dst[i] = bf16r_(s3[i-368640]);
}

// ------- x_proj -> padded/reordered SPLIT bf16 weights [192][384] (hi + lo) -------
// row = k*48 + j; j=0..11 <- c=j (dts), j=12..15 <- 0, j=16..47 <- c=j-4 (B then C)
__global__ void k_prepx(const float* __restrict__ xp, unsigned short* __restrict__ wXhi,
                        unsigned short* __restrict__ wXlo){
  int idx = blockIdx.x*256 + threadIdx.x;
  if (idx >= 192*384) return;
  int row = idx / 384, d = idx % 384;
  int k = row / 48, j = row % 48;
  float v = 0.f;
  if (j < 12) v = xp[(k*CP + j)*DI + d];
  else if (j >= 16) v = xp[(k*CP + (j-4))*DI + d];
  unsigned short hi = bf16r_(v);
  wXhi[idx] = hi;
  wXlo[idx] = bf16r_(v - bf2f_(hi));
}

// ---------------- depthwise 3x3 + residual (NHWC, C=192) ----------------
__global__ void k_dwconv_res(const float* __restrict__ in, const float* __restrict__ wgt,
                             const float* __restrict__ bias, float* __restrict__ out) {
  int idx = blockIdx.x*256 + threadIdx.x;
  const int total = BB*HHH*WWW*CC;
  if (idx >= total) return;
  int c = idx % CC;
  int w = (idx / CC) % WWW;
  int h = (idx / (CC*WWW)) % HHH;
  int b = idx / (CC*WWW*HHH);
  float acc = bias[c];
  #pragma unroll
  for (int kh=0; kh<3; kh++){
    int hh = h + kh - 1; if (hh < 0 || hh >= HHH) continue;
    #pragma unroll
    for (int kw=0; kw<3; kw++){
      int ww = w + kw - 1; if (ww < 0 || ww >= WWW) continue;
      acc += in[((b*HHH+hh)*WWW+ww)*CC + c] * wgt[c*9 + kh*3 + kw];
    }
  }
  out[idx] = in[idx] + acc;
}

// ---------------- LayerNorm over D=192, one wave per row, bf16 out ----------------
__global__ void k_ln192(const float* __restrict__ in, const float* __restrict__ g,
                        const float* __restrict__ bta, unsigned short* __restrict__ out, float eps) {
  int row = blockIdx.x*4 + (threadIdx.x>>6);
  int lane = threadIdx.x & 63;
  const float* p = in + (size_t)row*CC;
  float v0=p[lane], v1=p[lane+64], v2=p[lane+128];
  float s = v0+v1+v2, s2 = v0*v0+v1*v1+v2*v2;
  #pragma unroll
  for (int off=1; off<64; off<<=1){ s += __shfl_xor(s,off); s2 += __shfl_xor(s2,off); }
  float m = s*(1.f/192.f);
  float var = s2*(1.f/192.f) - m*m;
  float rstd = rsqrtf(var + eps);
  unsigned short* q = out + (size_t)row*CC;
  q[lane]     = bf16r_((v0-m)*rstd*g[lane]     + bta[lane]);
  q[lane+64]  = bf16r_((v1-m)*rstd*g[lane+64]  + bta[lane+64]);
  q[lane+128] = bf16r_((v2-m)*rstd*g[lane+128] + bta[lane+128]);
}

// ---------------- bf16 MFMA GEMM: out(MxN) = A(MxK) * W(NxK)^T ----------------
enum { EPI_NONE=0, EPI_RES=1, EPI_BIAS_GELU=2, EPI_BIAS_RES=3 };

template<int EPI, int OUTBF>
__global__ __launch_bounds__(256) void k_gemm_mfma(const unsigned short* __restrict__ A,
      const unsigned short* __restrict__ W, const float* __restrict__ bias,
      const float* __restrict__ res, void* __restrict__ outp, int M, int Nn, int Kk) {
  __shared__ unsigned short As[128][40];
  __shared__ unsigned short Bs[64][40];
  int tid = threadIdx.x;
  int m0 = blockIdx.y*128, n0 = blockIdx.x*64;
  int wid = tid>>6, lane = tid&63;
  int wm = wid*32;
  int fr = lane&15, fk = (lane>>4)*8;
  f32x4 acc[2][4];
  #pragma unroll
  for (int i=0;i<2;i++)
    #pragma unroll
    for (int j=0;j<4;j++) acc[i][j] = (f32x4){0.f,0.f,0.f,0.f};
  int arow = tid>>1, ak = (tid&1)*16;
  int wrow = tid>>2, wk = (tid&3)*8;
  const unsigned short* Ap = A + (size_t)(m0+arow)*Kk + ak;
  const unsigned short* Wp = W + (size_t)(n0+wrow)*Kk + wk;
  for (int k0=0; k0<Kk; k0+=32){
    __syncthreads();
    uint4 av0 = *(const uint4*)(Ap + k0);
    uint4 av1 = *(const uint4*)(Ap + k0 + 8);
    uint4 wv  = *(const uint4*)(Wp + k0);
    *(uint4*)&As[arow][ak]   = av0;
    *(uint4*)&As[arow][ak+8] = av1;
    *(uint4*)&Bs[wrow][wk]   = wv;
    __syncthreads();
    bf16x8 af[2], bfr[4];
    #pragma unroll
    for (int mi=0;mi<2;mi++) af[mi] = *(const bf16x8*)&As[wm + mi*16 + fr][fk];
    #pragma unroll
    for (int ni=0;ni<4;ni++) bfr[ni] = *(const bf16x8*)&Bs[ni*16 + fr][fk];
    #pragma unroll
    for (int mi=0;mi<2;mi++)
      #pragma unroll
      for (int ni=0;ni<4;ni++)
        acc[mi][ni] = __builtin_amdgcn_mfma_f32_16x16x32_bf16(af[mi], bfr[ni], acc[mi][ni], 0,0,0);
  }
  int rbase = (lane>>4)*4;
  #pragma unroll
  for (int mi=0;mi<2;mi++){
    #pragma unroll
    for (int ni=0;ni<4;ni++){
      int col = n0 + ni*16 + fr;
      float bv = (EPI==EPI_BIAS_GELU || EPI==EPI_BIAS_RES) ? bias[col] : 0.f;
      #pragma unroll
      for (int r=0;r<4;r++){
        int row = m0 + wm + mi*16 + rbase + r;
        float v = acc[mi][ni][r] + bv;
        if (EPI==EPI_BIAS_GELU) v = geluf_(v);
        if (EPI==EPI_RES || EPI==EPI_BIAS_RES) v += res[(size_t)row*Nn + col];
        if (OUTBF) ((unsigned short*)outp)[(size_t)row*Nn + col] = bf16r_(v);
        else       ((float*)outp)[(size_t)row*Nn + col] = v;
      }
    }
  }
}

// ------- x_dbl split-bf16 GEMM: u_f32(BLx384) * wX(192x384)^T, scatter to records -------
__global__ __launch_bounds__(256) void k_xgemm(const float* __restrict__ uf,
      const unsigned short* __restrict__ wXhi, const unsigned short* __restrict__ wXlo,
      float* __restrict__ xdblT) {
  __shared__ unsigned short Ah[64][40];
  __shared__ unsigned short Al[64][40];
  __shared__ unsigned short Bh[64][40];
  __shared__ unsigned short Bl[64][40];
  int tid = threadIdx.x;
  int m0 = blockIdx.y*64, n0 = blockIdx.x*64;
  int wid = tid>>6, lane = tid&63;
  int fr = lane&15, fk = (lane>>4)*8;
  f32x4 acc[4];
  #pragma unroll
  for (int j=0;j<4;j++) acc[j] = (f32x4){0.f,0.f,0.f,0.f};
  int srow = tid>>2, sk = (tid&3)*8;
  const float* Ap = uf + (size_t)(m0+srow)*DI + sk;
  const unsigned short* Wh = wXhi + (size_t)(n0+srow)*DI + sk;
  const unsigned short* Wl = wXlo + (size_t)(n0+srow)*DI + sk;
  for (int k0=0; k0<DI; k0+=32){
    __syncthreads();
    float4 ua = *(const float4*)(Ap + k0);
    float4 ub = *(const float4*)(Ap + k0 + 4);
    uint4 wh = *(const uint4*)(Wh + k0);
    uint4 wl = *(const uint4*)(Wl + k0);
    float uv[8] = {ua.x,ua.y,ua.z,ua.w, ub.x,ub.y,ub.z,ub.w};
    #pragma unroll
    for (int j=0;j<8;j++){
      unsigned short hi = bf16r_(uv[j]);
      Ah[srow][sk+j] = hi;
      Al[srow][sk+j] = bf16r_(uv[j] - bf2f_(hi));
    }
    *(uint4*)&Bh[srow][sk] = wh;
    *(uint4*)&Bl[srow][sk] = wl;
    __syncthreads();
    bf16x8 ah = *(const bf16x8*)&Ah[wid*16 + fr][fk];
    bf16x8 al = *(const bf16x8*)&Al[wid*16 + fr][fk];
    #pragma unroll
    for (int ni=0;ni<4;ni++){
      bf16x8 bh = *(const bf16x8*)&Bh[ni*16 + fr][fk];
      bf16x8 bl = *(const bf16x8*)&Bl[ni*16 + fr][fk];
      acc[ni] = __builtin_amdgcn_mfma_f32_16x16x32_bf16(ah, bh, acc[ni], 0,0,0);
      acc[ni] = __builtin_amdgcn_mfma_f32_16x16x32_bf16(al, bh, acc[ni], 0,0,0);
      acc[ni] = __builtin_amdgcn_mfma_f32_16x16x32_bf16(ah, bl, acc[ni], 0,0,0);
    }
  }
  int rbase = (lane>>4)*4;
  #pragma unroll
  for (int ni=0;ni<4;ni++){
    int col = n0 + ni*16 + fr;
    int k = col / 48, j = col % 48;
    #pragma unroll
    for (int r=0;r<4;r++){
      int row = m0 + wid*16 + rbase + r;
      int b = row / LL, s = row % LL;
      int h = s / WWW, w2 = s % WWW;
      int l1 = w2*HHH + h;
      int lk = (k==0) ? s : (k==1) ? l1 : (k==2) ? (LL-1-s) : (LL-1-l1);
      xdblT[((size_t)((b*KK+k)*LL + lk))*48 + j] = acc[ni][r];
    }
  }
}

// ---- depthwise conv 3x3 + bias + SiLU -> fp32 u in both sequence layouts ----
__global__ void k_conv_xx(const float* __restrict__ xz, const float* __restrict__ cw,
                          const float* __restrict__ cb, float* __restrict__ xc0,
                          float* __restrict__ xc1) {
  int idx = blockIdx.x*256 + threadIdx.x;
  if (idx >= BB*LL*DI) return;
  int d = idx % DI;
  int l = (idx / DI) % LL;
  int b = idx / (DI*LL);
  int h = l / WWW, w = l % WWW;
  float acc = cb[d];
  #pragma unroll
  for (int kh=0; kh<3; kh++){
    int hh = h + kh - 1; if (hh < 0 || hh >= HHH) continue;
    #pragma unroll
    for (int kw=0; kw<3; kw++){
      int ww2 = w + kw - 1; if (ww2 < 0 || ww2 >= WWW) continue;
      acc += xz[((size_t)(b*LL + hh*WWW + ww2))*(2*DI) + d] * cw[d*9 + kh*3 + kw];
    }
  }
  float v = siluf_(acc);
  xc0[idx] = v;
  xc1[((size_t)(b*LL + w*HHH + h))*DI + d] = v;
}

// ======== chunked selective scan, d-per-lane, single-wave blocks ========
template<int PASS>
__global__ __launch_bounds__(64) void k_scan(const float* __restrict__ xc_l0,
        const float* __restrict__ xc_l1,
        const float* __restrict__ xdblT, const float* __restrict__ dtw, const float* __restrict__ dtb,
        const float* __restrict__ alogs, const float* __restrict__ Dsv,
        float* __restrict__ hend, float* __restrict__ sumdt, unsigned short* __restrict__ ysb) {
  int ch = blockIdx.y, bk = blockIdx.z;
  int b = bk >> 2, k = bk & 3;
  int d = blockIdx.x*64 + threadIdx.x;
  int kd = k*DI + d;
  float w[12];
  #pragma unroll
  for (int r=0;r<12;r++) w[r] = dtw[kd*12 + r];
  float biasd = dtb[kd];
  float Dd = (PASS==1) ? Dsv[kd] : 0.f;
  float An2[16];
  #pragma unroll
  for (int n=0;n<16;n++) An2[n] = -__expf(alogs[kd*16 + n]) * 1.44269504f;
  bool pw = true;
  #pragma unroll
  for (int n=1;n<16;n++) pw = pw && (fabsf(An2[n] - (float)(n+1)*An2[0]) <= 1e-3f*(float)(n+1)*fabsf(An2[0]));
  const float* usrc = (k & 1) ? xc_l1 : xc_l0;
  bool rev = (k >= 2);
  const float* rec0 = xdblT + ((size_t)bk*LL + ch*CHL)*48;
  float h[16];
  size_t hb = ((size_t)(bk*NCH + ch)*DI + d)*16;
  if (PASS==0){
    #pragma unroll
    for (int n=0;n<16;n++) h[n]=0.f;
  } else {
    #pragma unroll
    for (int n4=0;n4<4;n4++){
      float4 hv = *(const float4*)&hend[hb + n4*4];
      h[n4*4]=hv.x; h[n4*4+1]=hv.y; h[n4*4+2]=hv.z; h[n4*4+3]=hv.w;
    }
  }
  float cum = 0.f;
  #pragma unroll 2
  for (int i=0;i<CHL;i++){
    int li = ch*CHL + i;
    int lsrc = rev ? (LL-1-li) : li;
    float uu = usrc[((size_t)(b*LL + lsrc))*DI + d];
    const float* rec = rec0 + (size_t)i*48;
    float4 t0 = *(const float4*)(rec);
    float4 t1 = *(const float4*)(rec+4);
    float4 t2 = *(const float4*)(rec+8);
    float4 B0 = *(const float4*)(rec+16);
    float4 B1 = *(const float4*)(rec+20);
    float4 B2 = *(const float4*)(rec+24);
    float4 B3 = *(const float4*)(rec+28);
    float a0 = fmaf(t0.x,w[0], fmaf(t0.y,w[1], fmaf(t0.z,w[2], t0.w*w[3])));
    float a1 = fmaf(t1.x,w[4], fmaf(t1.y,w[5], fmaf(t1.z,w[6], t1.w*w[7])));
    float a2 = fmaf(t2.x,w[8], fmaf(t2.y,w[9], fmaf(t2.z,w[10], t2.w*w[11])));
    float a = biasd + a0 + (a1 + a2);
    float dt = 0.69314718f * log2f(1.f + exp2f(a*1.44269504f));
    float dtu = dt*uu;
    if (PASS==0) cum += dt;
    float dA[16];
    if (pw){
      float r = exp2f(dt*An2[0]);
      float p = r; dA[0] = p;
      #pragma unroll
      for (int n=1;n<16;n++){ p *= r; dA[n] = p; }
    } else {
      #pragma unroll
      for (int n=0;n<16;n++) dA[n] = exp2f(dt*An2[n]);
    }
    float Bv[16] = {B0.x,B0.y,B0.z,B0.w, B1.x,B1.y,B1.z,B1.w,
                    B2.x,B2.y,B2.z,B2.w, B3.x,B3.y,B3.z,B3.w};
    #pragma unroll
    for (int n=0;n<16;n++) h[n] = fmaf(dA[n], h[n], dtu*Bv[n]);
    if (PASS==1){
      float4 C0 = *(const float4*)(rec+32);
      float4 C1 = *(const float4*)(rec+36);
      float4 C2 = *(const float4*)(rec+40);
      float4 C3 = *(const float4*)(rec+44);
      float y0 = fmaf(h[0], C0.x, fmaf(h[1], C0.y, fmaf(h[2], C0.z, h[3]*C0.w)));
      float y1 = fmaf(h[4], C1.x, fmaf(h[5], C1.y, fmaf(h[6], C1.z, h[7]*C1.w)));
      float y2 = fmaf(h[8], C2.x, fmaf(h[9], C2.y, fmaf(h[10],C2.z, h[11]*C2.w)));
      float y3 = fmaf(h[12],C3.x, fmaf(h[13],C3.y, fmaf(h[14],C3.z, h[15]*C3.w)));
      float y = fmaf(uu, Dd, (y0+y1)+(y2+y3));
      ysb[((size_t)(bk*LL + li))*DI + d] = bf16r_(y);
    }
  }
  if (PASS==0){
    #pragma unroll
    for (int n4=0;n4<4;n4++)
      *(float4*)&hend[hb + n4*4] = make_float4(h[n4*4],h[n4*4+1],h[n4*4+2],h[n4*4+3]);
    sumdt[(bk*NCH + ch)*DI + d] = cum;
  }
}

// S2: per (b,k,4d-block) wave: prefix over chunks; hend[c] <- incoming state H_{c-1}
__global__ __launch_bounds__(64) void k_scanmid(const float* __restrict__ alogs,
        const float* __restrict__ sumdt, float* __restrict__ hend) {
  int bid = blockIdx.x;
  int dblk = bid % 96;
  int k = (bid/96) % KK;
  int b = bid/(96*KK);
  int lane = threadIdx.x;
  int d4 = lane>>4, n = lane&15;
  int d = dblk*4 + d4;
  int bk = b*KK + k;
  float Ac2 = -__expf(alogs[(k*DI+d)*16 + n]) * 1.44269504f;
  float H = 0.f;
  for (int c=0;c<NCH;c++){
    float sdt = sumdt[(bk*NCH + c)*DI + d];
    float aexp = exp2f(Ac2 * sdt);
    size_t idx = ((size_t)(bk*NCH + c)*DI + dblk*4)*16 + lane;
    float tmp = hend[idx];
    hend[idx] = H;
    H = fmaf(aexp, H, tmp);
  }
}

// ---------------- fused combine + LN(Di) + silu(z) gate -> a2 (B,L,Di) bf16 ----------------
__global__ __launch_bounds__(384) void k_fuse(const unsigned short* __restrict__ ysb,
      const float* __restrict__ xz, const float* __restrict__ og, const float* __restrict__ ob,
      unsigned short* __restrict__ a2) {
  __shared__ float sa[6], sb[6];
  int b = blockIdx.x / LL, l = blockIdx.x % LL;
  int d = threadIdx.x;
  int h_ = l / WWW, w_ = l % WWW;
  int l1 = w_*HHH + h_;
  float y = bf2f_(ysb[((size_t)((b*KK+0)*LL + l))*DI + d])
          + bf2f_(ysb[((size_t)((b*KK+1)*LL + l1))*DI + d])
          + bf2f_(ysb[((size_t)((b*KK+2)*LL + (LL-1-l)))*DI + d])
          + bf2f_(ysb[((size_t)((b*KK+3)*LL + (LL-1-l1)))*DI + d]);
  float s = y, s2 = y*y;
  #pragma unroll
  for (int off=1; off<64; off<<=1){ s += __shfl_xor(s,off); s2 += __shfl_xor(s2,off); }
  int wid = d >> 6;
  if ((d & 63) == 0){ sa[wid] = s; sb[wid] = s2; }
  __syncthreads();
  s = sa[0]+sa[1]+sa[2]+sa[3]+sa[4]+sa[5];
  s2 = sb[0]+sb[1]+sb[2]+sb[3]+sb[4]+sb[5];
  float m = s*(1.f/DI);
  float var = s2*(1.f/DI) - m*m;
  float rstd = rsqrtf(var + 1e-5f);
  float v = (y - m)*rstd*og[d] + ob[d];
  float z = xz[((size_t)(b*LL + l))*(2*DI) + DI + d];
  a2[((size_t)(b*LL + l))*DI + d] = bf16r_(v * siluf_(z));
}

extern "C" void kernel_launch(void* const* d_in, const int* in_sizes, int n_in,
                              void* d_out, int out_size, void* d_ws, size_t ws_size,
                              hipStream_t stream) {
  (void)in_sizes; (void)n_in; (void)out_size; (void)ws_size;
  const float* x       = (const float*)d_in[0];
  const float* cpe1_w  = (const float*)d_in[1];
  const float* cpe1_b  = (const float*)d_in[2];
  const float* ln1_g   = (const float*)d_in[3];
  const float* ln1_b   = (const float*)d_in[4];
  const float* in_proj = (const float*)d_in[5];
  const float* conv_w  = (const float*)d_in[6];
  const float* conv_b  = (const float*)d_in[7];
  const float* x_proj  = (const float*)d_in[8];
  const float* dt_w    = (const float*)d_in[9];
  const float* dt_b    = (const float*)d_in[10];
  const float* A_logs  = (const float*)d_in[11];
  const float* Dsv     = (const float*)d_in[12];
  const float* onorm_g = (const float*)d_in[13];
  const float* onorm_b = (const float*)d_in[14];
  const float* out_proj= (const float*)d_in[15];
  const float* cpe2_w  = (const float*)d_in[16];
  const float* cpe2_b  = (const float*)d_in[17];
  const float* ln2_g   = (const float*)d_in[18];
  const float* ln2_b   = (const float*)d_in[19];
  const float* fc1_w   = (const float*)d_in[20];
  const float* fc1_b   = (const float*)d_in[21];
  const float* fc2_w   = (const float*)d_in[22];
  const float* fc2_b   = (const float*)d_in[23];
  float* out = (float*)d_out;
  float* wsf = (float*)d_ws;

  float* x1    = wsf;                        // 1,204,224 f
  float* xlnf  = x1 + 1204224;               // 1,204,224 f
  float* xz    = xlnf + 1204224;             // 4,816,896 f
  float* xc_l0 = xz + 4816896;               // 2,408,448 f  (B,L,Di) fp32
  float* xc_l1 = xc_l0 + 2408448;            // 2,408,448 f  (B,L1,Di) fp32
  float* ysbf  = xc_l1 + 2408448;            // 4,816,896 f = 9,633,792 bf16 (bk,L,Di)
  float* hend  = ysbf + 4816896;             // 4,816,896 f  (bk,NCH,Di,16)
  float* sumdt = hend + 4816896;             // 301,056 f
  float* xdblT = sumdt + 301056;             // 1,204,224 f
  unsigned short* wbf = (unsigned short*)(xdblT + 1204224); // 516,096 bf16 = 258,048 f
  unsigned short* wXhi = (unsigned short*)(wbf + 516096);   // 73,728 bf16
  unsigned short* wXlo = wXhi + 73728;                      // 73,728 bf16
  // total ~ 23.5M f ~ 94.1 MB
  // aliases (lifetime-disjoint)
  unsigned short* xln  = (unsigned short*)xlnf;
  unsigned short* xln2 = (unsigned short*)xlnf;
  unsigned short* ysb = (unsigned short*)ysbf;
  unsigned short* a2 = (unsigned short*)xdblT;   // after scan2 (2,408,448 bf16 fits)
  float* x2   = xc_l0;                           // after k_fuse
  float* x3   = xz;                              // after k_fuse
  unsigned short* hbuf = (unsigned short*)ysbf;  // after k_fuse
  unsigned short* wIn  = wbf;
  unsigned short* wOut = wbf + 147456;
  unsigned short* wF1  = wbf + 221184;
  unsigned short* wF2  = wbf + 368640;

  k_cvtw<<<2016, 256, 0, stream>>>(in_proj, out_proj, fc1_w, fc2_w, wbf);
  k_prepx<<<288, 256, 0, stream>>>(x_proj, wXhi, wXlo);
  k_dwconv_res<<<(BB*HHH*WWW*CC+255)/256, 256, 0, stream>>>(x, cpe1_w, cpe1_b, x1);
  k_ln192<<<BL/4, 256, 0, stream>>>(x1, ln1_g, ln1_b, xln, 1e-6f);
  k_gemm_mfma<EPI_NONE,0><<<dim3(768/64, BL/128), 256, 0, stream>>>(xln, wIn, nullptr, nullptr, xz, BL, 2*DI, CC);
  k_conv_xx<<<(BB*LL*DI+255)/256, 256, 0, stream>>>(xz, conv_w, conv_b, xc_l0, xc_l1);
  k_xgemm<<<dim3(3, BL/64), 256, 0, stream>>>(xc_l0, wXhi, wXlo, xdblT);
  k_scan<0><<<dim3(6, NCH, BB*KK), 64, 0, stream>>>(xc_l0, xc_l1, xdblT, dt_w, dt_b, A_logs, Dsv, hend, sumdt, ysb);
  k_scanmid<<<BB*KK*96, 64, 0, stream>>>(A_logs, sumdt, hend);
  k_scan<1><<<dim3(6, NCH, BB*KK), 64, 0, stream>>>(xc_l0, xc_l1, xdblT, dt_w, dt_b, A_logs, Dsv, hend, sumdt, ysb);
  k_fuse<<<BB*LL, 384, 0, stream>>>(ysb, xz, onorm_g, onorm_b, a2);
  k_gemm_mfma<EPI_RES,0><<<dim3(192/64, BL/128), 256, 0, stream>>>(a2, wOut, nullptr, x1, x2, BL, CC, DI);
  k_dwconv_res<<<(BB*HHH*WWW*CC+255)/256, 256, 0, stream>>>(x2, cpe2_w, cpe2_b, x3);
  k_ln192<<<BL/4, 256, 0, stream>>>(x3, ln2_g, ln2_b, xln2, 1e-6f);
  k_gemm_mfma<EPI_BIAS_GELU,1><<<dim3(768/64, BL/128), 256, 0, stream>>>(xln2, wF1, fc1_b, nullptr, hbuf, BL, HIDN, CC);
  k_gemm_mfma<EPI_BIAS_RES,0><<<dim3(192/64, BL/128), 256, 0, stream>>>(hbuf, wF2, fc2_b, x3, out, BL, CC, HIDN);
}

// Round 8
// 242.960 us; speedup vs baseline: 3.6107x; 1.0149x over previous
//
#include <hip/hip_runtime.h>
#include <math.h>

#define BB 2
#define HHH 56
#define WWW 56
#define CC 192
#define LL 3136
#define DI 384
#define KK 4
#define NN 16
#define RR 12
#define CP 44
#define HIDN 768
#define BL (BB*LL)
#define NCH 98   // chunks per sequence
#define CHL 32   // chunk length (98*32 = 3136)

typedef __attribute__((ext_vector_type(8))) short bf16x8;
typedef __attribute__((ext_vector_type(4))) float f32x4;

__device__ __forceinline__ float siluf_(float x){ return x/(1.f+__expf(-x)); }
__device__ __forceinline__ float geluf_(float x){ return 0.5f*x*(1.f+erff(x*0.70710678118654752f)); }
__device__ __forceinline__ unsigned short bf16r_(float x){
  unsigned int u = __float_as_uint(x);
  u += 0x7FFFu + ((u>>16)&1u);
  return (unsigned short)(u>>16);
}
__device__ __forceinline__ float bf2f_(unsigned short u){
  return __uint_as_float(((unsigned int)u)<<16);
}

// ---------------- weight fp32 -> bf16 convert (4 segments) ----------------
__global__ void k_cvtw(const float* __restrict__ s0, const float* __restrict__ s1,
                       const float* __restrict__ s2, const float* __restrict__ s3,
                       unsigned short* __restrict__ dst){
  int i = blockIdx.x*256 + threadIdx.x;
  if      (i < 147456) dst[i] = bf16r_(s0[i]);
  else if (i < 221184) dst[i] = bf16r_(s1[i-147456]);
  else if (i < 368640) dst[i] = bf16r_(s2[i-221184]);
  else if (i < 516096) dst[i] = bf16r_(s3[i-368640]);
}

// ------- x_proj -> padded/reordered SPLIT bf16 weights [192][384] (hi + lo) -------
// row = k*48 + j; j=0..11 <- c=j (dts), j=12..15 <- 0, j=16..47 <- c=j-4 (B then C)
__global__ void k_prepx(const float* __restrict__ xp, unsigned short* __restrict__ wXhi,
                        unsigned short* __restrict__ wXlo){
  int idx = blockIdx.x*256 + threadIdx.x;
  if (idx >= 192*384) return;
  int row = idx / 384, d = idx % 384;
  int k = row / 48, j = row % 48;
  float v = 0.f;
  if (j < 12) v = xp[(k*CP + j)*DI + d];
  else if (j >= 16) v = xp[(k*CP + (j-4))*DI + d];
  unsigned short hi = bf16r_(v);
  wXhi[idx] = hi;
  wXlo[idx] = bf16r_(v - bf2f_(hi));
}

// ---------------- depthwise 3x3 + residual (NHWC, C=192) ----------------
__global__ void k_dwconv_res(const float* __restrict__ in, const float* __restrict__ wgt,
                             const float* __restrict__ bias, float* __restrict__ out) {
  int idx = blockIdx.x*256 + threadIdx.x;
  const int total = BB*HHH*WWW*CC;
  if (idx >= total) return;
  int c = idx % CC;
  int w = (idx / CC) % WWW;
  int h = (idx / (CC*WWW)) % HHH;
  int b = idx / (CC*WWW*HHH);
  float acc = bias[c];
  #pragma unroll
  for (int kh=0; kh<3; kh++){
    int hh = h + kh - 1; if (hh < 0 || hh >= HHH) continue;
    #pragma unroll
    for (int kw=0; kw<3; kw++){
      int ww = w + kw - 1; if (ww < 0 || ww >= WWW) continue;
      acc += in[((b*HHH+hh)*WWW+ww)*CC + c] * wgt[c*9 + kh*3 + kw];
    }
  }
  out[idx] = in[idx] + acc;
}

// ---------------- LayerNorm over D=192, one wave per row, bf16 out ----------------
__global__ void k_ln192(const float* __restrict__ in, const float* __restrict__ g,
                        const float* __restrict__ bta, unsigned short* __restrict__ out, float eps) {
  int row = blockIdx.x*4 + (threadIdx.x>>6);
  int lane = threadIdx.x & 63;
  const float* p = in + (size_t)row*CC;
  float v0=p[lane], v1=p[lane+64], v2=p[lane+128];
  float s = v0+v1+v2, s2 = v0*v0+v1*v1+v2*v2;
  #pragma unroll
  for (int off=1; off<64; off<<=1){ s += __shfl_xor(s,off); s2 += __shfl_xor(s2,off); }
  float m = s*(1.f/192.f);
  float var = s2*(1.f/192.f) - m*m;
  float rstd = rsqrtf(var + eps);
  unsigned short* q = out + (size_t)row*CC;
  q[lane]     = bf16r_((v0-m)*rstd*g[lane]     + bta[lane]);
  q[lane+64]  = bf16r_((v1-m)*rstd*g[lane+64]  + bta[lane+64]);
  q[lane+128] = bf16r_((v2-m)*rstd*g[lane+128] + bta[lane+128]);
}

// ------- bf16 MFMA GEMM: out(MxN) = A(MxK)*W(NxK)^T; MT = M-tile (128 or 64) -------
enum { EPI_NONE=0, EPI_RES=1, EPI_BIAS_GELU=2, EPI_BIAS_RES=3 };

template<int MT, int EPI, int OUTBF>
__global__ __launch_bounds__(256) void k_gemm_mfma(const unsigned short* __restrict__ A,
      const unsigned short* __restrict__ W, const float* __restrict__ bias,
      const float* __restrict__ res, void* __restrict__ outp, int M, int Nn, int Kk) {
  __shared__ unsigned short As[MT][40];
  __shared__ unsigned short Bs[64][40];
  constexpr int NI = (MT==128) ? 4 : 2;
  int tid = threadIdx.x;
  int m0 = blockIdx.y*MT, n0 = blockIdx.x*64;
  int wid = tid>>6, lane = tid&63;
  int wm = (MT==128) ? wid*32 : (wid&1)*32;
  int wn = (MT==128) ? 0 : (wid>>1)*32;
  int fr = lane&15, fk = (lane>>4)*8;
  f32x4 acc[2][NI];
  #pragma unroll
  for (int i=0;i<2;i++)
    #pragma unroll
    for (int j=0;j<NI;j++) acc[i][j] = (f32x4){0.f,0.f,0.f,0.f};
  int arow, ak;
  if (MT==128){ arow = tid>>1; ak = (tid&1)*16; }
  else        { arow = tid>>2; ak = (tid&3)*8;  }
  int wrow = tid>>2, wk = (tid&3)*8;
  const unsigned short* Ap = A + (size_t)(m0+arow)*Kk + ak;
  const unsigned short* Wp = W + (size_t)(n0+wrow)*Kk + wk;
  for (int k0=0; k0<Kk; k0+=32){
    __syncthreads();
    if (MT==128){
      uint4 av0 = *(const uint4*)(Ap + k0);
      uint4 av1 = *(const uint4*)(Ap + k0 + 8);
      *(uint4*)&As[arow][ak]   = av0;
      *(uint4*)&As[arow][ak+8] = av1;
    } else {
      *(uint4*)&As[arow][ak] = *(const uint4*)(Ap + k0);
    }
    *(uint4*)&Bs[wrow][wk] = *(const uint4*)(Wp + k0);
    __syncthreads();
    bf16x8 af[2], bfr[NI];
    #pragma unroll
    for (int mi=0;mi<2;mi++) af[mi] = *(const bf16x8*)&As[wm + mi*16 + fr][fk];
    #pragma unroll
    for (int ni=0;ni<NI;ni++) bfr[ni] = *(const bf16x8*)&Bs[wn + ni*16 + fr][fk];
    #pragma unroll
    for (int mi=0;mi<2;mi++)
      #pragma unroll
      for (int ni=0;ni<NI;ni++)
        acc[mi][ni] = __builtin_amdgcn_mfma_f32_16x16x32_bf16(af[mi], bfr[ni], acc[mi][ni], 0,0,0);
  }
  int rbase = (lane>>4)*4;
  #pragma unroll
  for (int mi=0;mi<2;mi++){
    #pragma unroll
    for (int ni=0;ni<NI;ni++){
      int col = n0 + wn + ni*16 + fr;
      float bv = (EPI==EPI_BIAS_GELU || EPI==EPI_BIAS_RES) ? bias[col] : 0.f;
      #pragma unroll
      for (int r=0;r<4;r++){
        int row = m0 + wm + mi*16 + rbase + r;
        float v = acc[mi][ni][r] + bv;
        if (EPI==EPI_BIAS_GELU) v = geluf_(v);
        if (EPI==EPI_RES || EPI==EPI_BIAS_RES) v += res[(size_t)row*Nn + col];
        if (OUTBF) ((unsigned short*)outp)[(size_t)row*Nn + col] = bf16r_(v);
        else       ((float*)outp)[(size_t)row*Nn + col] = v;
      }
    }
  }
}

// ------- x_dbl split-bf16 GEMM: u_f32(BLx384) * wX(192x384)^T, scatter to records -------
__global__ __launch_bounds__(256) void k_xgemm(const float* __restrict__ uf,
      const unsigned short* __restrict__ wXhi, const unsigned short* __restrict__ wXlo,
      float* __restrict__ xdblT) {
  __shared__ unsigned short Ah[64][40];
  __shared__ unsigned short Al[64][40];
  __shared__ unsigned short Bh[64][40];
  __shared__ unsigned short Bl[64][40];
  int tid = threadIdx.x;
  int m0 = blockIdx.y*64, n0 = blockIdx.x*64;
  int wid = tid>>6, lane = tid&63;
  int fr = lane&15, fk = (lane>>4)*8;
  f32x4 acc[4];
  #pragma unroll
  for (int j=0;j<4;j++) acc[j] = (f32x4){0.f,0.f,0.f,0.f};
  int srow = tid>>2, sk = (tid&3)*8;
  const float* Ap = uf + (size_t)(m0+srow)*DI + sk;
  const unsigned short* Wh = wXhi + (size_t)(n0+srow)*DI + sk;
  const unsigned short* Wl = wXlo + (size_t)(n0+srow)*DI + sk;
  for (int k0=0; k0<DI; k0+=32){
    __syncthreads();
    float4 ua = *(const float4*)(Ap + k0);
    float4 ub = *(const float4*)(Ap + k0 + 4);
    uint4 wh = *(const uint4*)(Wh + k0);
    uint4 wl = *(const uint4*)(Wl + k0);
    float uv[8] = {ua.x,ua.y,ua.z,ua.w, ub.x,ub.y,ub.z,ub.w};
    #pragma unroll
    for (int j=0;j<8;j++){
      unsigned short hi = bf16r_(uv[j]);
      Ah[srow][sk+j] = hi;
      Al[srow][sk+j] = bf16r_(uv[j] - bf2f_(hi));
    }
    *(uint4*)&Bh[srow][sk] = wh;
    *(uint4*)&Bl[srow][sk] = wl;
    __syncthreads();
    bf16x8 ah = *(const bf16x8*)&Ah[wid*16 + fr][fk];
    bf16x8 al = *(const bf16x8*)&Al[wid*16 + fr][fk];
    #pragma unroll
    for (int ni=0;ni<4;ni++){
      bf16x8 bh = *(const bf16x8*)&Bh[ni*16 + fr][fk];
      bf16x8 bl = *(const bf16x8*)&Bl[ni*16 + fr][fk];
      acc[ni] = __builtin_amdgcn_mfma_f32_16x16x32_bf16(ah, bh, acc[ni], 0,0,0);
      acc[ni] = __builtin_amdgcn_mfma_f32_16x16x32_bf16(al, bh, acc[ni], 0,0,0);
      acc[ni] = __builtin_amdgcn_mfma_f32_16x16x32_bf16(ah, bl, acc[ni], 0,0,0);
    }
  }
  int rbase = (lane>>4)*4;
  #pragma unroll
  for (int ni=0;ni<4;ni++){
    int col = n0 + ni*16 + fr;
    int k = col / 48, j = col % 48;
    #pragma unroll
    for (int r=0;r<4;r++){
      int row = m0 + wid*16 + rbase + r;
      int b = row / LL, s = row % LL;
      int h = s / WWW, w2 = s % WWW;
      int l1 = w2*HHH + h;
      int lk = (k==0) ? s : (k==1) ? l1 : (k==2) ? (LL-1-s) : (LL-1-l1);
      xdblT[((size_t)((b*KK+k)*LL + lk))*48 + j] = acc[ni][r];
    }
  }
}

// ---- depthwise conv 3x3 + bias + SiLU -> fp32 u in both sequence layouts ----
__global__ void k_conv_xx(const float* __restrict__ xz, const float* __restrict__ cw,
                          const float* __restrict__ cb, float* __restrict__ xc0,
                          float* __restrict__ xc1) {
  int idx = blockIdx.x*256 + threadIdx.x;
  if (idx >= BB*LL*DI) return;
  int d = idx % DI;
  int l = (idx / DI) % LL;
  int b = idx / (DI*LL);
  int h = l / WWW, w = l % WWW;
  float acc = cb[d];
  #pragma unroll
  for (int kh=0; kh<3; kh++){
    int hh = h + kh - 1; if (hh < 0 || hh >= HHH) continue;
    #pragma unroll
    for (int kw=0; kw<3; kw++){
      int ww2 = w + kw - 1; if (ww2 < 0 || ww2 >= WWW) continue;
      acc += xz[((size_t)(b*LL + hh*WWW + ww2))*(2*DI) + d] * cw[d*9 + kh*3 + kw];
    }
  }
  float v = siluf_(acc);
  xc0[idx] = v;
  xc1[((size_t)(b*LL + w*HHH + h))*DI + d] = v;
}

// ======== chunked selective scan, d-per-lane, single-wave blocks, bf16 hend ========
template<int PASS>
__global__ __launch_bounds__(64) void k_scan(const float* __restrict__ xc_l0,
        const float* __restrict__ xc_l1,
        const float* __restrict__ xdblT, const float* __restrict__ dtw, const float* __restrict__ dtb,
        const float* __restrict__ alogs, const float* __restrict__ Dsv,
        unsigned short* __restrict__ hend, float* __restrict__ sumdt, unsigned short* __restrict__ ysb) {
  int ch = blockIdx.y, bk = blockIdx.z;
  int b = bk >> 2, k = bk & 3;
  int d = blockIdx.x*64 + threadIdx.x;
  int kd = k*DI + d;
  float w[12];
  #pragma unroll
  for (int r=0;r<12;r++) w[r] = dtw[kd*12 + r];
  float biasd = dtb[kd];
  float Dd = (PASS==1) ? Dsv[kd] : 0.f;
  float An2[16];
  #pragma unroll
  for (int n=0;n<16;n++) An2[n] = -__expf(alogs[kd*16 + n]) * 1.44269504f;
  bool pw = true;
  #pragma unroll
  for (int n=1;n<16;n++) pw = pw && (fabsf(An2[n] - (float)(n+1)*An2[0]) <= 1e-3f*(float)(n+1)*fabsf(An2[0]));
  const float* usrc = (k & 1) ? xc_l1 : xc_l0;
  bool rev = (k >= 2);
  const float* rec0 = xdblT + ((size_t)bk*LL + ch*CHL)*48;
  float h[16];
  size_t hb = ((size_t)(bk*NCH + ch)*DI + d)*16;
  if (PASS==0){
    #pragma unroll
    for (int n=0;n<16;n++) h[n]=0.f;
  } else {
    uint4 q0 = *(const uint4*)&hend[hb];
    uint4 q1 = *(const uint4*)&hend[hb+8];
    unsigned int qa[8] = {q0.x,q0.y,q0.z,q0.w, q1.x,q1.y,q1.z,q1.w};
    #pragma unroll
    for (int j=0;j<8;j++){
      h[2*j]   = bf2f_((unsigned short)(qa[j] & 0xffffu));
      h[2*j+1] = bf2f_((unsigned short)(qa[j] >> 16));
    }
  }
  float cum = 0.f;
  #pragma unroll 2
  for (int i=0;i<CHL;i++){
    int li = ch*CHL + i;
    int lsrc = rev ? (LL-1-li) : li;
    float uu = usrc[((size_t)(b*LL + lsrc))*DI + d];
    const float* rec = rec0 + (size_t)i*48;
    float4 t0 = *(const float4*)(rec);
    float4 t1 = *(const float4*)(rec+4);
    float4 t2 = *(const float4*)(rec+8);
    float4 B0 = *(const float4*)(rec+16);
    float4 B1 = *(const float4*)(rec+20);
    float4 B2 = *(const float4*)(rec+24);
    float4 B3 = *(const float4*)(rec+28);
    float a0 = fmaf(t0.x,w[0], fmaf(t0.y,w[1], fmaf(t0.z,w[2], t0.w*w[3])));
    float a1 = fmaf(t1.x,w[4], fmaf(t1.y,w[5], fmaf(t1.z,w[6], t1.w*w[7])));
    float a2 = fmaf(t2.x,w[8], fmaf(t2.y,w[9], fmaf(t2.z,w[10], t2.w*w[11])));
    float a = biasd + a0 + (a1 + a2);
    float dt = 0.69314718f * log2f(1.f + exp2f(a*1.44269504f));
    float dtu = dt*uu;
    if (PASS==0) cum += dt;
    float dA[16];
    if (pw){
      float r1 = exp2f(dt*An2[0]);
      float r2 = r1*r1;
      float r3 = r2*r1;
      float r4 = r2*r2;
      float r8 = r4*r4;
      dA[0]=r1;     dA[1]=r2;     dA[2]=r3;     dA[3]=r4;
      dA[4]=r4*r1;  dA[5]=r4*r2;  dA[6]=r4*r3;  dA[7]=r8;
      dA[8]=r8*r1;  dA[9]=r8*r2;  dA[10]=r8*r3; dA[11]=r8*r4;
      dA[12]=r8*dA[4]; dA[13]=r8*dA[5]; dA[14]=r8*dA[6]; dA[15]=r8*r8;
    } else {
      #pragma unroll
      for (int n=0;n<16;n++) dA[n] = exp2f(dt*An2[n]);
    }
    float Bv[16] = {B0.x,B0.y,B0.z,B0.w, B1.x,B1.y,B1.z,B1.w,
                    B2.x,B2.y,B2.z,B2.w, B3.x,B3.y,B3.z,B3.w};
    #pragma unroll
    for (int n=0;n<16;n++) h[n] = fmaf(dA[n], h[n], dtu*Bv[n]);
    if (PASS==1){
      float4 C0 = *(const float4*)(rec+32);
      float4 C1 = *(const float4*)(rec+36);
      float4 C2 = *(const float4*)(rec+40);
      float4 C3 = *(const float4*)(rec+44);
      float y0 = fmaf(h[0], C0.x, fmaf(h[1], C0.y, fmaf(h[2], C0.z, h[3]*C0.w)));
      float y1 = fmaf(h[4], C1.x, fmaf(h[5], C1.y, fmaf(h[6], C1.z, h[7]*C1.w)));
      float y2 = fmaf(h[8], C2.x, fmaf(h[9], C2.y, fmaf(h[10],C2.z, h[11]*C2.w)));
      float y3 = fmaf(h[12],C3.x, fmaf(h[13],C3.y, fmaf(h[14],C3.z, h[15]*C3.w)));
      float y = fmaf(uu, Dd, (y0+y1)+(y2+y3));
      ysb[((size_t)(bk*LL + li))*DI + d] = bf16r_(y);
    }
  }
  if (PASS==0){
    unsigned int pk[8];
    #pragma unroll
    for (int j=0;j<8;j++)
      pk[j] = ((unsigned int)bf16r_(h[2*j+1])<<16) | (unsigned int)bf16r_(h[2*j]);
    *(uint4*)&hend[hb]   = make_uint4(pk[0],pk[1],pk[2],pk[3]);
    *(uint4*)&hend[hb+8] = make_uint4(pk[4],pk[5],pk[6],pk[7]);
    sumdt[(bk*NCH + ch)*DI + d] = cum;
  }
}

// S2: per (b,k,4d-block) wave: prefix over chunks; hend[c] <- incoming state H_{c-1} (bf16)
__global__ __launch_bounds__(64) void k_scanmid(const float* __restrict__ alogs,
        const float* __restrict__ sumdt, unsigned short* __restrict__ hend) {
  int bid = blockIdx.x;
  int dblk = bid % 96;
  int k = (bid/96) % KK;
  int b = bid/(96*KK);
  int lane = threadIdx.x;
  int d4 = lane>>4, n = lane&15;
  int d = dblk*4 + d4;
  int bk = b*KK + k;
  float Ac2 = -__expf(alogs[(k*DI+d)*16 + n]) * 1.44269504f;
  float H = 0.f;
  for (int c=0;c<NCH;c++){
    float sdt = sumdt[(bk*NCH + c)*DI + d];
    float aexp = exp2f(Ac2 * sdt);
    size_t idx = ((size_t)(bk*NCH + c)*DI + dblk*4)*16 + lane;
    float tmp = bf2f_(hend[idx]);
    hend[idx] = bf16r_(H);
    H = fmaf(aexp, H, tmp);
  }
}

// ---------------- fused combine + LN(Di) + silu(z) gate -> a2 (B,L,Di) bf16 ----------------
__global__ __launch_bounds__(384) void k_fuse(const unsigned short* __restrict__ ysb,
      const float* __restrict__ xz, const float* __restrict__ og, const float* __restrict__ ob,
      unsigned short* __restrict__ a2) {
  __shared__ float sa[6], sb[6];
  int b = blockIdx.x / LL, l = blockIdx.x % LL;
  int d = threadIdx.x;
  int h_ = l / WWW, w_ = l % WWW;
  int l1 = w_*HHH + h_;
  float y = bf2f_(ysb[((size_t)((b*KK+0)*LL + l))*DI + d])
          + bf2f_(ysb[((size_t)((b*KK+1)*LL + l1))*DI + d])
          + bf2f_(ysb[((size_t)((b*KK+2)*LL + (LL-1-l)))*DI + d])
          + bf2f_(ysb[((size_t)((b*KK+3)*LL + (LL-1-l1)))*DI + d]);
  float s = y, s2 = y*y;
  #pragma unroll
  for (int off=1; off<64; off<<=1){ s += __shfl_xor(s,off); s2 += __shfl_xor(s2,off); }
  int wid = d >> 6;
  if ((d & 63) == 0){ sa[wid] = s; sb[wid] = s2; }
  __syncthreads();
  s = sa[0]+sa[1]+sa[2]+sa[3]+sa[4]+sa[5];
  s2 = sb[0]+sb[1]+sb[2]+sb[3]+sb[4]+sb[5];
  float m = s*(1.f/DI);
  float var = s2*(1.f/DI) - m*m;
  float rstd = rsqrtf(var + 1e-5f);
  float v = (y - m)*rstd*og[d] + ob[d];
  float z = xz[((size_t)(b*LL + l))*(2*DI) + DI + d];
  a2[((size_t)(b*LL + l))*DI + d] = bf16r_(v * siluf_(z));
}

extern "C" void kernel_launch(void* const* d_in, const int* in_sizes, int n_in,
                              void* d_out, int out_size, void* d_ws, size_t ws_size,
                              hipStream_t stream) {
  (void)in_sizes; (void)n_in; (void)out_size; (void)ws_size;
  const float* x       = (const float*)d_in[0];
  const float* cpe1_w  = (const float*)d_in[1];
  const float* cpe1_b  = (const float*)d_in[2];
  const float* ln1_g   = (const float*)d_in[3];
  const float* ln1_b   = (const float*)d_in[4];
  const float* in_proj = (const float*)d_in[5];
  const float* conv_w  = (const float*)d_in[6];
  const float* conv_b  = (const float*)d_in[7];
  const float* x_proj  = (const float*)d_in[8];
  const float* dt_w    = (const float*)d_in[9];
  const float* dt_b    = (const float*)d_in[10];
  const float* A_logs  = (const float*)d_in[11];
  const float* Dsv     = (const float*)d_in[12];
  const float* onorm_g = (const float*)d_in[13];
  const float* onorm_b = (const float*)d_in[14];
  const float* out_proj= (const float*)d_in[15];
  const float* cpe2_w  = (const float*)d_in[16];
  const float* cpe2_b  = (const float*)d_in[17];
  const float* ln2_g   = (const float*)d_in[18];
  const float* ln2_b   = (const float*)d_in[19];
  const float* fc1_w   = (const float*)d_in[20];
  const float* fc1_b   = (const float*)d_in[21];
  const float* fc2_w   = (const float*)d_in[22];
  const float* fc2_b   = (const float*)d_in[23];
  float* out = (float*)d_out;
  float* wsf = (float*)d_ws;

  float* x1    = wsf;                        // 1,204,224 f
  float* xlnf  = x1 + 1204224;               // 1,204,224 f
  float* xz    = xlnf + 1204224;             // 4,816,896 f
  float* xc_l0 = xz + 4816896;               // 2,408,448 f  (B,L,Di) fp32
  float* xc_l1 = xc_l0 + 2408448;            // 2,408,448 f  (B,L1,Di) fp32
  float* ysbf  = xc_l1 + 2408448;            // 4,816,896 f = 9,633,792 bf16 (bk,L,Di)
  float* hendf = ysbf + 4816896;             // 2,408,448 f = 4,816,896 bf16 (bk,NCH,Di,16)
  float* sumdt = hendf + 2408448;            // 301,056 f
  float* xdblT = sumdt + 301056;             // 1,204,224 f
  unsigned short* wbf = (unsigned short*)(xdblT + 1204224); // 516,096 bf16
  unsigned short* wXhi = wbf + 516096;       // 73,728 bf16
  unsigned short* wXlo = wXhi + 73728;       // 73,728 bf16
  // aliases (lifetime-disjoint)
  unsigned short* xln  = (unsigned short*)xlnf;
  unsigned short* xln2 = (unsigned short*)xlnf;
  unsigned short* ysb  = (unsigned short*)ysbf;
  unsigned short* hend = (unsigned short*)hendf;
  unsigned short* a2   = (unsigned short*)xdblT;  // after scan2
  float* x2   = xc_l0;                            // after k_fuse
  float* x3   = xz;                               // after k_fuse
  unsigned short* hbuf = (unsigned short*)ysbf;   // after k_fuse
  unsigned short* wIn  = wbf;
  unsigned short* wOut = wbf + 147456;
  unsigned short* wF1  = wbf + 221184;
  unsigned short* wF2  = wbf + 368640;

  k_cvtw<<<2016, 256, 0, stream>>>(in_proj, out_proj, fc1_w, fc2_w, wbf);
  k_prepx<<<288, 256, 0, stream>>>(x_proj, wXhi, wXlo);
  k_dwconv_res<<<(BB*HHH*WWW*CC+255)/256, 256, 0, stream>>>(x, cpe1_w, cpe1_b, x1);
  k_ln192<<<BL/4, 256, 0, stream>>>(x1, ln1_g, ln1_b, xln, 1e-6f);
  k_gemm_mfma<128,EPI_NONE,0><<<dim3(768/64, BL/128), 256, 0, stream>>>(xln, wIn, nullptr, nullptr, xz, BL, 2*DI, CC);
  k_conv_xx<<<(BB*LL*DI+255)/256, 256, 0, stream>>>(xz, conv_w, conv_b, xc_l0, xc_l1);
  k_xgemm<<<dim3(3, BL/64), 256, 0, stream>>>(xc_l0, wXhi, wXlo, xdblT);
  k_scan<0><<<dim3(6, NCH, BB*KK), 64, 0, stream>>>(xc_l0, xc_l1, xdblT, dt_w, dt_b, A_logs, Dsv, hend, sumdt, ysb);
  k_scanmid<<<BB*KK*96, 64, 0, stream>>>(A_logs, sumdt, hend);
  k_scan<1><<<dim3(6, NCH, BB*KK), 64, 0, stream>>>(xc_l0, xc_l1, xdblT, dt_w, dt_b, A_logs, Dsv, hend, sumdt, ysb);
  k_fuse<<<BB*LL, 384, 0, stream>>>(ysb, xz, onorm_g, onorm_b, a2);
  k_gemm_mfma<64,EPI_RES,0><<<dim3(192/64, BL/64), 256, 0, stream>>>(a2, wOut, nullptr, x1, x2, BL, CC, DI);
  k_dwconv_res<<<(BB*HHH*WWW*CC+255)/256, 256, 0, stream>>>(x2, cpe2_w, cpe2_b, x3);
  k_ln192<<<BL/4, 256, 0, stream>>>(x3, ln2_g, ln2_b, xln2, 1e-6f);
  k_gemm_mfma<128,EPI_BIAS_GELU,1><<<dim3(768/64, BL/128), 256, 0, stream>>>(xln2, wF1, fc1_b, nullptr, hbuf, BL, HIDN, CC);
  k_gemm_mfma<64,EPI_BIAS_RES,0><<<dim3(192/64, BL/64), 256, 0, stream>>>(hbuf, wF2, fc2_b, x3, out, BL, CC, HIDN);
}